// Round 1
// baseline (1853.145 us; speedup 1.0000x reference)
//
#include <hip/hip_runtime.h>
#include <hip/hip_bf16.h>
#include <math.h>

#define L_   1024
#define DM_  2048
#define DI_  4096
#define DR_  128
#define DS_  16
#define DBC_ 160   // DR + 2*DS

// ---------------- RMSNorm: xn = x * rsqrt(mean(x^2)+eps) * w ----------------
__launch_bounds__(256)
__global__ void rmsnorm_kernel(const float* __restrict__ x, const float* __restrict__ w,
                               float* __restrict__ xn) {
  int l = blockIdx.x;
  const float4* xr = (const float4*)(x + (size_t)l * DM_);
  const float4* wr = (const float4*)w;
  float4 v0 = xr[threadIdx.x];
  float4 v1 = xr[threadIdx.x + 256];
  float ss = v0.x*v0.x + v0.y*v0.y + v0.z*v0.z + v0.w*v0.w
           + v1.x*v1.x + v1.y*v1.y + v1.z*v1.z + v1.w*v1.w;
  for (int off = 32; off > 0; off >>= 1) ss += __shfl_down(ss, off, 64);
  __shared__ float sbuf[4];
  int lane = threadIdx.x & 63, wid = threadIdx.x >> 6;
  if (lane == 0) sbuf[wid] = ss;
  __syncthreads();
  float tot = sbuf[0] + sbuf[1] + sbuf[2] + sbuf[3];
  float scale = rsqrtf(tot / (float)DM_ + 1e-5f);
  float4 w0 = wr[threadIdx.x], w1 = wr[threadIdx.x + 256];
  float4 o0, o1;
  o0.x = v0.x * scale * w0.x; o0.y = v0.y * scale * w0.y;
  o0.z = v0.z * scale * w0.z; o0.w = v0.w * scale * w0.w;
  o1.x = v1.x * scale * w1.x; o1.y = v1.y * scale * w1.y;
  o1.z = v1.z * scale * w1.z; o1.w = v1.w * scale * w1.w;
  float4* outr = (float4*)(xn + (size_t)l * DM_);
  outr[threadIdx.x] = o0;
  outr[threadIdx.x + 256] = o1;
}

// ---------------- Generic NT GEMM: C[m][n] = sum_k A[m][k]*W[n][k] ----------
// EPI 0: store; EPI 1: softplus(acc + aux[n]); EPI 2: acc + aux[m*ldc+n]
template<int EPI>
__launch_bounds__(256)
__global__ void gemm_nt(const float* __restrict__ A, const float* __restrict__ W,
                        float* __restrict__ C, int M, int N, int Kd,
                        int lda, int ldw, int ldc,
                        const float* __restrict__ aux) {
  __shared__ float As[16][68];
  __shared__ float Ws[16][68];
  int bm = blockIdx.y * 64, bn = blockIdx.x * 64;
  int tid = threadIdx.x;
  int tr = (tid >> 4) << 2;   // 0..60
  int tc = (tid & 15) << 2;   // 0..60
  float acc[4][4] = {};
  for (int k0 = 0; k0 < Kd; k0 += 16) {
#pragma unroll
    for (int i = 0; i < 4; i++) {
      int f = tid + i * 256;
      int r = f >> 4, c = f & 15;
      As[c][r] = A[(size_t)(bm + r) * lda + k0 + c];
    }
#pragma unroll
    for (int i = 0; i < 4; i++) {
      int f = tid + i * 256;
      int r = f >> 4, c = f & 15;
      Ws[c][r] = W[(size_t)(bn + r) * ldw + k0 + c];
    }
    __syncthreads();
#pragma unroll
    for (int k = 0; k < 16; k++) {
      float4 av = *(const float4*)&As[k][tr];
      float4 wv = *(const float4*)&Ws[k][tc];
      float a_[4] = {av.x, av.y, av.z, av.w};
      float w_[4] = {wv.x, wv.y, wv.z, wv.w};
#pragma unroll
      for (int i = 0; i < 4; i++)
#pragma unroll
        for (int j = 0; j < 4; j++)
          acc[i][j] = fmaf(a_[i], w_[j], acc[i][j]);
    }
    __syncthreads();
  }
#pragma unroll
  for (int i = 0; i < 4; i++) {
    int row = bm + tr + i;
#pragma unroll
    for (int j = 0; j < 4; j++) {
      int col = bn + tc + j;
      float v = acc[i][j];
      if (EPI == 1) {
        v += aux[col];
        v = fmaxf(v, 0.f) + log1pf(__expf(-fabsf(v)));
      }
      if (EPI == 2) {
        v += aux[(size_t)row * ldc + col];
      }
      C[(size_t)row * ldc + col] = v;
    }
  }
}

// ---------------- depthwise conv1d (K=3, pad 1) + SiLU ----------------------
__launch_bounds__(256)
__global__ void conv_silu_kernel(const float* __restrict__ xz, const float* __restrict__ cw,
                                 const float* __restrict__ cb, float* __restrict__ xc) {
  int idx = blockIdx.x * 256 + threadIdx.x;  // over L*DI
  int l = idx >> 12, d = idx & (DI_ - 1);
  float w0 = cw[d * 3 + 0], w1 = cw[d * 3 + 1], w2 = cw[d * 3 + 2];
  float acc = cb[d];
  const float* base = xz + d;  // xs[l][d] = xz[l*2*DI + d]
  if (l > 0)      acc = fmaf(w0, base[(size_t)(l - 1) * (2 * DI_)], acc);
  acc = fmaf(w1, base[(size_t)l * (2 * DI_)], acc);
  if (l < L_ - 1) acc = fmaf(w2, base[(size_t)(l + 1) * (2 * DI_)], acc);
  float sig = 1.f / (1.f + __expf(-acc));
  xc[idx] = acc * sig;
}

// ---------------- An = -exp(A_log) ------------------------------------------
__global__ void negexp_kernel(const float* __restrict__ a, float* __restrict__ o, int n) {
  int i = blockIdx.x * 256 + threadIdx.x;
  if (i < n) o[i] = -__expf(a[i]);
}

// ---------------- skinny GEMM: dBC[l][n] = sum_k xc[l][k]*x_proj_w[n][k] ----
__launch_bounds__(256)
__global__ void gemm_xproj(const float* __restrict__ xc, const float* __restrict__ W,
                           float* __restrict__ dBC) {
  __shared__ float xs[4][DI_];  // 64 KB
  int l0 = blockIdx.x * 4;
  const float4* src = (const float4*)(xc + (size_t)l0 * DI_);
  float4* dst = (float4*)&xs[0][0];
  for (int i = threadIdx.x; i < 4 * DI_ / 4; i += 256) dst[i] = src[i];
  __syncthreads();
  int wave = threadIdx.x >> 6, lane = threadIdx.x & 63;
  for (int n = wave * 40; n < (wave + 1) * 40; n++) {
    const float* wr = W + (size_t)n * DI_;
    float s0 = 0.f, s1 = 0.f, s2 = 0.f, s3 = 0.f;
    for (int k = lane; k < DI_; k += 64) {
      float wv = wr[k];
      s0 = fmaf(xs[0][k], wv, s0);
      s1 = fmaf(xs[1][k], wv, s1);
      s2 = fmaf(xs[2][k], wv, s2);
      s3 = fmaf(xs[3][k], wv, s3);
    }
    for (int off = 32; off > 0; off >>= 1) {
      s0 += __shfl_down(s0, off, 64);
      s1 += __shfl_down(s1, off, 64);
      s2 += __shfl_down(s2, off, 64);
      s3 += __shfl_down(s3, off, 64);
    }
    if (lane == 0) {
      dBC[(size_t)(l0 + 0) * DBC_ + n] = s0;
      dBC[(size_t)(l0 + 1) * DBC_ + n] = s1;
      dBC[(size_t)(l0 + 2) * DBC_ + n] = s2;
      dBC[(size_t)(l0 + 3) * DBC_ + n] = s3;
    }
  }
}

// ---------------- SSM elementwise: h_new, y, yz = y*silu(z) -----------------
__launch_bounds__(256)
__global__ void ssm_kernel(const float* __restrict__ xz, const float* __restrict__ xc,
                           const float* __restrict__ dBC, const float* __restrict__ delta,
                           const float* __restrict__ h, const float* __restrict__ An,
                           const float* __restrict__ Dp, float* __restrict__ h_out,
                           float* __restrict__ yz) {
  int idx = blockIdx.x * 256 + threadIdx.x;  // over L*DI
  int l = idx >> 12, d = idx & (DI_ - 1);
  float dv = delta[idx];
  float xv = xc[idx];
  const float* Br = dBC + (size_t)l * DBC_ + DR_;
  const float* Cr = Br + DS_;
  const float4* hr = (const float4*)(h + (size_t)idx * DS_);
  const float4* Ar = (const float4*)(An + (size_t)d * DS_);
  float4* ho = (float4*)(h_out + (size_t)idx * DS_);
  float y = 0.f;
#pragma unroll
  for (int q = 0; q < 4; q++) {
    float4 hv = hr[q];
    float4 Av = Ar[q];
    float4 Bv = *(const float4*)&Br[q * 4];
    float4 Cv = *(const float4*)&Cr[q * 4];
    float4 hn;
    hn.x = __expf(dv * Av.x) * hv.x + dv * Bv.x * xv;
    hn.y = __expf(dv * Av.y) * hv.y + dv * Bv.y * xv;
    hn.z = __expf(dv * Av.z) * hv.z + dv * Bv.z * xv;
    hn.w = __expf(dv * Av.w) * hv.w + dv * Bv.w * xv;
    y = fmaf(hn.x, Cv.x, y);
    y = fmaf(hn.y, Cv.y, y);
    y = fmaf(hn.z, Cv.z, y);
    y = fmaf(hn.w, Cv.w, y);
    ho[q] = hn;
  }
  y = fmaf(Dp[d], xv, y);
  float zv = xz[(size_t)l * (2 * DI_) + DI_ + d];
  float sig = 1.f / (1.f + __expf(-zv));
  yz[idx] = y * zv * sig;
}

extern "C" void kernel_launch(void* const* d_in, const int* in_sizes, int n_in,
                              void* d_out, int out_size, void* d_ws, size_t ws_size,
                              hipStream_t stream) {
  const float* x         = (const float*)d_in[0];
  const float* h         = (const float*)d_in[1];
  const float* norm_w    = (const float*)d_in[2];
  const float* in_proj_w = (const float*)d_in[3];
  const float* conv_w    = (const float*)d_in[4];
  const float* conv_b    = (const float*)d_in[5];
  const float* x_proj_w  = (const float*)d_in[6];
  const float* dt_proj_w = (const float*)d_in[7];
  const float* dt_proj_b = (const float*)d_in[8];
  const float* A_log     = (const float*)d_in[9];
  const float* Dvec      = (const float*)d_in[10];
  const float* out_projw = (const float*)d_in[11];

  float* out   = (float*)d_out;
  float* h_out = out + (size_t)L_ * DM_;

  float* ws    = (float*)d_ws;
  float* xn    = ws;                               // 2,097,152
  float* xz    = xn    + (size_t)L_ * DM_;         // 8,388,608
  float* xc    = xz    + (size_t)L_ * 2 * DI_;     // 4,194,304
  float* dBC   = xc    + (size_t)L_ * DI_;         // 163,840
  float* delta = dBC   + (size_t)L_ * DBC_;        // 4,194,304
  float* yz    = delta + (size_t)L_ * DI_;         // 4,194,304
  float* An    = yz    + (size_t)L_ * DI_;         // 65,536
  // total ~23.3M floats ≈ 93 MB

  // 1. RMSNorm
  rmsnorm_kernel<<<L_, 256, 0, stream>>>(x, norm_w, xn);
  // 2. xz = xn @ in_proj_w.T   [1024 x 8192], K=2048
  gemm_nt<0><<<dim3(2 * DI_ / 64, L_ / 64), 256, 0, stream>>>(
      xn, in_proj_w, xz, L_, 2 * DI_, DM_, DM_, DM_, 2 * DI_, nullptr);
  // 3. depthwise conv + silu -> xc
  conv_silu_kernel<<<L_ * DI_ / 256, 256, 0, stream>>>(xz, conv_w, conv_b, xc);
  // 4. An = -exp(A_log)
  negexp_kernel<<<(DI_ * DS_) / 256, 256, 0, stream>>>(A_log, An, DI_ * DS_);
  // 5. dBC = xc @ x_proj_w.T   [1024 x 160], K=4096
  gemm_xproj<<<L_ / 4, 256, 0, stream>>>(xc, x_proj_w, dBC);
  // 6. delta = softplus(dBC[:, :128] @ dt_proj_w.T + dt_proj_b)  [1024 x 4096]
  gemm_nt<1><<<dim3(DI_ / 64, L_ / 64), 256, 0, stream>>>(
      dBC, dt_proj_w, delta, L_, DI_, DR_, DBC_, DR_, DI_, dt_proj_b);
  // 7. SSM elementwise: h_new (to output) + yz
  ssm_kernel<<<L_ * DI_ / 256, 256, 0, stream>>>(
      xz, xc, dBC, delta, h, An, Dvec, h_out, yz);
  // 8. out = yz @ out_proj_w.T + xn   [1024 x 2048], K=4096
  gemm_nt<2><<<dim3(DM_ / 64, L_ / 64), 256, 0, stream>>>(
      yz, out_projw, out, L_, DM_, DI_, DI_, DI_, DM_, xn);
}

// Round 2
// 477.394 us; speedup vs baseline: 3.8818x; 3.8818x over previous
//
#include <hip/hip_runtime.h>
#include <hip/hip_bf16.h>
#include <math.h>

#define L_   1024
#define DM_  2048
#define DI_  4096
#define DR_  128
#define DS_  16
#define DBC_ 160   // DR + 2*DS

typedef __attribute__((ext_vector_type(4))) float f32x4;
typedef __attribute__((ext_vector_type(8))) short s16x8;

__device__ inline unsigned short f2b(float f) {  // RNE f32->bf16
  unsigned int u = __float_as_uint(f);
  u += 0x7fffu + ((u >> 16) & 1u);
  return (unsigned short)(u >> 16);
}

__device__ inline void gload_lds16(const void* g, void* l) {
  __builtin_amdgcn_global_load_lds(
      (const __attribute__((address_space(1))) void*)g,
      (__attribute__((address_space(3))) void*)l, 16, 0, 0);
}

// ---------------- RMSNorm: xn = x * rsqrt(mean(x^2)+eps) * w (f32 + bf16) ---
__launch_bounds__(256)
__global__ void rmsnorm_kernel(const float* __restrict__ x, const float* __restrict__ w,
                               float* __restrict__ xn, unsigned short* __restrict__ xnb) {
  int l = blockIdx.x;
  const float4* xr = (const float4*)(x + (size_t)l * DM_);
  const float4* wr = (const float4*)w;
  float4 v0 = xr[threadIdx.x];
  float4 v1 = xr[threadIdx.x + 256];
  float ss = v0.x*v0.x + v0.y*v0.y + v0.z*v0.z + v0.w*v0.w
           + v1.x*v1.x + v1.y*v1.y + v1.z*v1.z + v1.w*v1.w;
  for (int off = 32; off > 0; off >>= 1) ss += __shfl_down(ss, off, 64);
  __shared__ float sbuf[4];
  int lane = threadIdx.x & 63, wid = threadIdx.x >> 6;
  if (lane == 0) sbuf[wid] = ss;
  __syncthreads();
  float tot = sbuf[0] + sbuf[1] + sbuf[2] + sbuf[3];
  float scale = rsqrtf(tot / (float)DM_ + 1e-5f);
  float4 w0 = wr[threadIdx.x], w1 = wr[threadIdx.x + 256];
  float4 o0, o1;
  o0.x = v0.x * scale * w0.x; o0.y = v0.y * scale * w0.y;
  o0.z = v0.z * scale * w0.z; o0.w = v0.w * scale * w0.w;
  o1.x = v1.x * scale * w1.x; o1.y = v1.y * scale * w1.y;
  o1.z = v1.z * scale * w1.z; o1.w = v1.w * scale * w1.w;
  float4* outr = (float4*)(xn + (size_t)l * DM_);
  outr[threadIdx.x] = o0;
  outr[threadIdx.x + 256] = o1;
  uint2 p0, p1;
  p0.x = (unsigned)f2b(o0.x) | ((unsigned)f2b(o0.y) << 16);
  p0.y = (unsigned)f2b(o0.z) | ((unsigned)f2b(o0.w) << 16);
  p1.x = (unsigned)f2b(o1.x) | ((unsigned)f2b(o1.y) << 16);
  p1.y = (unsigned)f2b(o1.z) | ((unsigned)f2b(o1.w) << 16);
  uint2* ob = (uint2*)(xnb + (size_t)l * DM_);
  ob[threadIdx.x] = p0;
  ob[threadIdx.x + 256] = p1;
}

// ---------------- f32 -> bf16 bulk convert (n multiple of 4) ----------------
__launch_bounds__(256)
__global__ void f32_to_bf16_kernel(const float* __restrict__ in, unsigned short* __restrict__ out, int n4) {
  int i = blockIdx.x * 256 + threadIdx.x;
  if (i >= n4) return;
  float4 v = ((const float4*)in)[i];
  uint2 p;
  p.x = (unsigned)f2b(v.x) | ((unsigned)f2b(v.y) << 16);
  p.y = (unsigned)f2b(v.z) | ((unsigned)f2b(v.w) << 16);
  ((uint2*)out)[i] = p;
}

// ---------------- bf16 MFMA GEMM: C[m][n] = sum_k A[m][k]*W[n][k] -----------
// 128x128 tile, 4 waves (2x2), 4x4 16x16x32 frags/wave. EPI 0: store; 2: +aux
template<int EPI>
__launch_bounds__(256)
__global__ void gemm_bf16_mfma(const unsigned short* __restrict__ A,
                               const unsigned short* __restrict__ W,
                               float* __restrict__ C, int M, int N, int K,
                               const float* __restrict__ aux) {
  __shared__ unsigned short As[128 * 32];
  __shared__ unsigned short Ws[128 * 32];
  int bm = blockIdx.y * 128, bn = blockIdx.x * 128;
  int tid = threadIdx.x;
  int w = tid >> 6, lane = tid & 63;
  int wr = (w >> 1) * 64, wc = (w & 1) * 64;
  f32x4 acc[4][4];
#pragma unroll
  for (int m = 0; m < 4; m++)
#pragma unroll
    for (int n = 0; n < 4; n++) acc[m][n] = (f32x4){0.f, 0.f, 0.f, 0.f};

  int kb = lane >> 4, r = lane & 15;
  for (int k0 = 0; k0 < K; k0 += 32) {
#pragma unroll
    for (int i = 0; i < 2; i++) {
      int ch = (i * 4 + w) * 64 + lane;      // 0..511, lane-contiguous per wave
      int row = ch >> 2, kc = ch & 3;
      gload_lds16(A + (size_t)(bm + row) * K + k0 + kc * 8, As + ch * 8);
      gload_lds16(W + (size_t)(bn + row) * K + k0 + kc * 8, Ws + ch * 8);
    }
    asm volatile("s_waitcnt vmcnt(0)" ::: "memory");
    __syncthreads();
    s16x8 a[4], b[4];
#pragma unroll
    for (int m = 0; m < 4; m++)
      a[m] = *(const s16x8*)(As + (wr + m * 16 + r) * 32 + kb * 8);
#pragma unroll
    for (int n = 0; n < 4; n++)
      b[n] = *(const s16x8*)(Ws + (wc + n * 16 + r) * 32 + kb * 8);
#pragma unroll
    for (int m = 0; m < 4; m++)
#pragma unroll
      for (int n = 0; n < 4; n++)
        acc[m][n] = __builtin_amdgcn_mfma_f32_16x16x32_bf16(a[m], b[n], acc[m][n], 0, 0, 0);
    __syncthreads();
  }
  int q = lane >> 4;
#pragma unroll
  for (int m = 0; m < 4; m++) {
#pragma unroll
    for (int n = 0; n < 4; n++) {
#pragma unroll
      for (int j = 0; j < 4; j++) {
        int row = bm + wr + m * 16 + q * 4 + j;
        int col = bn + wc + n * 16 + r;
        float v = acc[m][n][j];
        if (EPI == 2) v += aux[(size_t)row * N + col];
        C[(size_t)row * N + col] = v;
      }
    }
  }
}

// ---------------- fp32 NT GEMM (kept for dt_proj): softplus epilogue --------
__launch_bounds__(256)
__global__ void gemm_nt_sp(const float* __restrict__ A, const float* __restrict__ W,
                           float* __restrict__ C, int M, int N, int Kd,
                           int lda, int ldw, int ldc,
                           const float* __restrict__ aux) {
  __shared__ float As[16][68];
  __shared__ float Ws[16][68];
  int bm = blockIdx.y * 64, bn = blockIdx.x * 64;
  int tid = threadIdx.x;
  int tr = (tid >> 4) << 2;
  int tc = (tid & 15) << 2;
  float acc[4][4] = {};
  for (int k0 = 0; k0 < Kd; k0 += 16) {
#pragma unroll
    for (int i = 0; i < 4; i++) {
      int f = tid + i * 256;
      int rr = f >> 4, c = f & 15;
      As[c][rr] = A[(size_t)(bm + rr) * lda + k0 + c];
    }
#pragma unroll
    for (int i = 0; i < 4; i++) {
      int f = tid + i * 256;
      int rr = f >> 4, c = f & 15;
      Ws[c][rr] = W[(size_t)(bn + rr) * ldw + k0 + c];
    }
    __syncthreads();
#pragma unroll
    for (int k = 0; k < 16; k++) {
      float4 av = *(const float4*)&As[k][tr];
      float4 wv = *(const float4*)&Ws[k][tc];
      float a_[4] = {av.x, av.y, av.z, av.w};
      float w_[4] = {wv.x, wv.y, wv.z, wv.w};
#pragma unroll
      for (int i = 0; i < 4; i++)
#pragma unroll
        for (int j = 0; j < 4; j++)
          acc[i][j] = fmaf(a_[i], w_[j], acc[i][j]);
    }
    __syncthreads();
  }
#pragma unroll
  for (int i = 0; i < 4; i++) {
    int row = bm + tr + i;
#pragma unroll
    for (int j = 0; j < 4; j++) {
      int col = bn + tc + j;
      float v = acc[i][j] + aux[col];
      v = fmaxf(v, 0.f) + log1pf(__expf(-fabsf(v)));
      C[(size_t)row * ldc + col] = v;
    }
  }
}

// ---------------- depthwise conv1d (K=3, pad 1) + SiLU ----------------------
__launch_bounds__(256)
__global__ void conv_silu_kernel(const float* __restrict__ xz, const float* __restrict__ cw,
                                 const float* __restrict__ cb, float* __restrict__ xc) {
  int idx = blockIdx.x * 256 + threadIdx.x;  // over L*DI
  int l = idx >> 12, d = idx & (DI_ - 1);
  float w0 = cw[d * 3 + 0], w1 = cw[d * 3 + 1], w2 = cw[d * 3 + 2];
  float acc = cb[d];
  const float* base = xz + d;
  if (l > 0)      acc = fmaf(w0, base[(size_t)(l - 1) * (2 * DI_)], acc);
  acc = fmaf(w1, base[(size_t)l * (2 * DI_)], acc);
  if (l < L_ - 1) acc = fmaf(w2, base[(size_t)(l + 1) * (2 * DI_)], acc);
  float sig = 1.f / (1.f + __expf(-acc));
  xc[idx] = acc * sig;
}

// ---------------- An = -exp(A_log) ------------------------------------------
__global__ void negexp_kernel(const float* __restrict__ a, float* __restrict__ o, int n) {
  int i = blockIdx.x * 256 + threadIdx.x;
  if (i < n) o[i] = -__expf(a[i]);
}

// ---------------- xproj split-K stage1: part[s][l][n] partial dots ----------
// grid: (16 k-splits, 16 row-tiles); block 256. Rows 64, cols 160, K-range 256.
__launch_bounds__(256)
__global__ void xproj_stage1(const float* __restrict__ xc, const float* __restrict__ W,
                             float* __restrict__ part) {
  __shared__ float xcs[64][68];
  __shared__ float Ws[160][68];
  int k0 = blockIdx.x * 256;
  int l0 = blockIdx.y * 64;
  int tid = threadIdx.x;
  int rg = tid >> 4;     // 0..15 -> rows rg*4..+3
  int cg = tid & 15;     // cols cg*10..+9
  float acc[4][10] = {};
  for (int kc = 0; kc < 256; kc += 64) {
    for (int i = tid; i < 64 * 16; i += 256) {
      int row = i >> 4, c4 = (i & 15) * 4;
      *(float4*)&xcs[row][c4] = *(const float4*)&xc[(size_t)(l0 + row) * DI_ + k0 + kc + c4];
    }
    for (int i = tid; i < 160 * 16; i += 256) {
      int row = i >> 4, c4 = (i & 15) * 4;
      *(float4*)&Ws[row][c4] = *(const float4*)&W[(size_t)row * DI_ + k0 + kc + c4];
    }
    __syncthreads();
#pragma unroll 4
    for (int k = 0; k < 64; k += 4) {
      float4 xa[4];
#pragma unroll
      for (int i = 0; i < 4; i++) xa[i] = *(const float4*)&xcs[rg * 4 + i][k];
#pragma unroll
      for (int j = 0; j < 10; j++) {
        float4 wv = *(const float4*)&Ws[cg * 10 + j][k];
#pragma unroll
        for (int i = 0; i < 4; i++) {
          float s = acc[i][j];
          s = fmaf(xa[i].x, wv.x, s);
          s = fmaf(xa[i].y, wv.y, s);
          s = fmaf(xa[i].z, wv.z, s);
          s = fmaf(xa[i].w, wv.w, s);
          acc[i][j] = s;
        }
      }
    }
    __syncthreads();
  }
  float* pb = part + ((size_t)blockIdx.x * L_ + l0) * DBC_;
#pragma unroll
  for (int i = 0; i < 4; i++)
#pragma unroll
    for (int j = 0; j < 10; j++)
      pb[(size_t)(rg * 4 + i) * DBC_ + cg * 10 + j] = acc[i][j];
}

// ---------------- xproj stage2: dBC = sum over 16 splits --------------------
__launch_bounds__(256)
__global__ void xproj_stage2(const float* __restrict__ part, float* __restrict__ dBC) {
  int i = blockIdx.x * 256 + threadIdx.x;  // over L*DBC
  float s = 0.f;
#pragma unroll
  for (int sp = 0; sp < 16; sp++) s += part[(size_t)sp * (L_ * DBC_) + i];
  dBC[i] = s;
}

// ---------------- SSM elementwise: h_new, y, yz=y*silu(z) (bf16 out) --------
__launch_bounds__(256)
__global__ void ssm_kernel(const float* __restrict__ xz, const float* __restrict__ xc,
                           const float* __restrict__ dBC, const float* __restrict__ delta,
                           const float* __restrict__ h, const float* __restrict__ An,
                           const float* __restrict__ Dp, float* __restrict__ h_out,
                           unsigned short* __restrict__ yzb) {
  int idx = blockIdx.x * 256 + threadIdx.x;  // over L*DI
  int l = idx >> 12, d = idx & (DI_ - 1);
  float dv = delta[idx];
  float xv = xc[idx];
  const float* Br = dBC + (size_t)l * DBC_ + DR_;
  const float* Cr = Br + DS_;
  const float4* hr = (const float4*)(h + (size_t)idx * DS_);
  const float4* Ar = (const float4*)(An + (size_t)d * DS_);
  float4* ho = (float4*)(h_out + (size_t)idx * DS_);
  float y = 0.f;
#pragma unroll
  for (int q = 0; q < 4; q++) {
    float4 hv = hr[q];
    float4 Av = Ar[q];
    float4 Bv = *(const float4*)&Br[q * 4];
    float4 Cv = *(const float4*)&Cr[q * 4];
    float4 hn;
    hn.x = __expf(dv * Av.x) * hv.x + dv * Bv.x * xv;
    hn.y = __expf(dv * Av.y) * hv.y + dv * Bv.y * xv;
    hn.z = __expf(dv * Av.z) * hv.z + dv * Bv.z * xv;
    hn.w = __expf(dv * Av.w) * hv.w + dv * Bv.w * xv;
    y = fmaf(hn.x, Cv.x, y);
    y = fmaf(hn.y, Cv.y, y);
    y = fmaf(hn.z, Cv.z, y);
    y = fmaf(hn.w, Cv.w, y);
    ho[q] = hn;
  }
  y = fmaf(Dp[d], xv, y);
  float zv = xz[(size_t)l * (2 * DI_) + DI_ + d];
  float sig = 1.f / (1.f + __expf(-zv));
  yzb[idx] = f2b(y * zv * sig);
}

extern "C" void kernel_launch(void* const* d_in, const int* in_sizes, int n_in,
                              void* d_out, int out_size, void* d_ws, size_t ws_size,
                              hipStream_t stream) {
  const float* x         = (const float*)d_in[0];
  const float* h         = (const float*)d_in[1];
  const float* norm_w    = (const float*)d_in[2];
  const float* in_proj_w = (const float*)d_in[3];
  const float* conv_w    = (const float*)d_in[4];
  const float* conv_b    = (const float*)d_in[5];
  const float* x_proj_w  = (const float*)d_in[6];
  const float* dt_proj_w = (const float*)d_in[7];
  const float* dt_proj_b = (const float*)d_in[8];
  const float* A_log     = (const float*)d_in[9];
  const float* Dvec      = (const float*)d_in[10];
  const float* out_projw = (const float*)d_in[11];

  float* out   = (float*)d_out;
  float* h_out = out + (size_t)L_ * DM_;

  float* ws    = (float*)d_ws;
  float* xn    = ws;                               // L*DM      = 2,097,152
  float* xz    = xn    + (size_t)L_ * DM_;         // L*2*DI    = 8,388,608
  float* xc    = xz    + (size_t)L_ * 2 * DI_;     // L*DI      = 4,194,304
  float* dBC   = xc    + (size_t)L_ * DI_;         // L*DBC     =   163,840
  float* delta = dBC   + (size_t)L_ * DBC_;        // L*DI      = 4,194,304
  float* An    = delta + (size_t)L_ * DI_;         // DI*DS     =    65,536
  float* part  = An    + (size_t)DI_ * DS_;        // 16*L*DBC  = 2,621,440
  unsigned short* xnb = (unsigned short*)(part + (size_t)16 * L_ * DBC_);
  unsigned short* wib = xnb + (size_t)L_ * DM_;          // 2*DI*DM = 16,777,216
  unsigned short* wob = wib + (size_t)2 * DI_ * DM_;     // DM*DI   =  8,388,608
  unsigned short* yzb = wob + (size_t)DM_ * DI_;         // L*DI    =  4,194,304
  // f32 ~87 MB + bf16 ~63 MB = ~150 MB of ws

  // 1. RMSNorm (f32 + bf16 outputs)
  rmsnorm_kernel<<<L_, 256, 0, stream>>>(x, norm_w, xn, xnb);
  // 1b. weight conversions
  f32_to_bf16_kernel<<<(2 * DI_ * DM_ / 4 + 255) / 256, 256, 0, stream>>>(in_proj_w, wib, 2 * DI_ * DM_ / 4);
  f32_to_bf16_kernel<<<(DM_ * DI_ / 4 + 255) / 256, 256, 0, stream>>>(out_projw, wob, DM_ * DI_ / 4);
  // 2. xz = xn @ in_proj_w.T   [1024 x 8192], K=2048  (bf16 MFMA)
  gemm_bf16_mfma<0><<<dim3(2 * DI_ / 128, L_ / 128), 256, 0, stream>>>(
      xnb, wib, xz, L_, 2 * DI_, DM_, nullptr);
  // 3. depthwise conv + silu -> xc
  conv_silu_kernel<<<L_ * DI_ / 256, 256, 0, stream>>>(xz, conv_w, conv_b, xc);
  // 4. An = -exp(A_log)
  negexp_kernel<<<(DI_ * DS_) / 256, 256, 0, stream>>>(A_log, An, DI_ * DS_);
  // 5. dBC = xc @ x_proj_w.T   [1024 x 160], K=4096  (split-K, 2 stages)
  xproj_stage1<<<dim3(16, 16), 256, 0, stream>>>(xc, x_proj_w, part);
  xproj_stage2<<<L_ * DBC_ / 256, 256, 0, stream>>>(part, dBC);
  // 6. delta = softplus(dBC[:, :128] @ dt_proj_w.T + dt_proj_b)  [1024 x 4096]
  gemm_nt_sp<<<dim3(DI_ / 64, L_ / 64), 256, 0, stream>>>(
      dBC, dt_proj_w, delta, L_, DI_, DR_, DBC_, DR_, DI_, dt_proj_b);
  // 7. SSM elementwise: h_new (to output) + yz (bf16)
  ssm_kernel<<<L_ * DI_ / 256, 256, 0, stream>>>(
      xz, xc, dBC, delta, h, An, Dvec, h_out, yzb);
  // 8. out = yz @ out_proj_w.T + xn   [1024 x 2048], K=4096  (bf16 MFMA)
  gemm_bf16_mfma<2><<<dim3(DM_ / 128, L_ / 128), 256, 0, stream>>>(
      yzb, wob, out, L_, DM_, DI_, xn);
}

// Round 4
// 392.990 us; speedup vs baseline: 4.7155x; 1.2148x over previous
//
#include <hip/hip_runtime.h>
#include <hip/hip_bf16.h>
#include <math.h>

#define L_   1024
#define DM_  2048
#define DI_  4096
#define DR_  128
#define DS_  16
#define DBC_ 160   // DR + 2*DS

typedef __attribute__((ext_vector_type(4))) float f32x4;
typedef __attribute__((ext_vector_type(8))) short s16x8;

__device__ inline unsigned short f2b(float f) {  // RNE f32->bf16
  unsigned int u = __float_as_uint(f);
  u += 0x7fffu + ((u >> 16) & 1u);
  return (unsigned short)(u >> 16);
}

__device__ inline void gload_lds16(const void* g, void* l) {
  __builtin_amdgcn_global_load_lds(
      (const __attribute__((address_space(1))) void*)g,
      (__attribute__((address_space(3))) void*)l, 16, 0, 0);
}

// ---------------- RMSNorm: xn = x * rsqrt(mean(x^2)+eps) * w (f32 + bf16) ---
__launch_bounds__(256)
__global__ void rmsnorm_kernel(const float* __restrict__ x, const float* __restrict__ w,
                               float* __restrict__ xn, unsigned short* __restrict__ xnb) {
  int l = blockIdx.x;
  const float4* xr = (const float4*)(x + (size_t)l * DM_);
  const float4* wr = (const float4*)w;
  float4 v0 = xr[threadIdx.x];
  float4 v1 = xr[threadIdx.x + 256];
  float ss = v0.x*v0.x + v0.y*v0.y + v0.z*v0.z + v0.w*v0.w
           + v1.x*v1.x + v1.y*v1.y + v1.z*v1.z + v1.w*v1.w;
  for (int off = 32; off > 0; off >>= 1) ss += __shfl_down(ss, off, 64);
  __shared__ float sbuf[4];
  int lane = threadIdx.x & 63, wid = threadIdx.x >> 6;
  if (lane == 0) sbuf[wid] = ss;
  __syncthreads();
  float tot = sbuf[0] + sbuf[1] + sbuf[2] + sbuf[3];
  float scale = rsqrtf(tot / (float)DM_ + 1e-5f);
  float4 w0 = wr[threadIdx.x], w1 = wr[threadIdx.x + 256];
  float4 o0, o1;
  o0.x = v0.x * scale * w0.x; o0.y = v0.y * scale * w0.y;
  o0.z = v0.z * scale * w0.z; o0.w = v0.w * scale * w0.w;
  o1.x = v1.x * scale * w1.x; o1.y = v1.y * scale * w1.y;
  o1.z = v1.z * scale * w1.z; o1.w = v1.w * scale * w1.w;
  float4* outr = (float4*)(xn + (size_t)l * DM_);
  outr[threadIdx.x] = o0;
  outr[threadIdx.x + 256] = o1;
  uint2 p0, p1;
  p0.x = (unsigned)f2b(o0.x) | ((unsigned)f2b(o0.y) << 16);
  p0.y = (unsigned)f2b(o0.z) | ((unsigned)f2b(o0.w) << 16);
  p1.x = (unsigned)f2b(o1.x) | ((unsigned)f2b(o1.y) << 16);
  p1.y = (unsigned)f2b(o1.z) | ((unsigned)f2b(o1.w) << 16);
  uint2* ob = (uint2*)(xnb + (size_t)l * DM_);
  ob[threadIdx.x] = p0;
  ob[threadIdx.x + 256] = p1;
}

// ---------------- f32 -> bf16 bulk convert (n multiple of 4) ----------------
__launch_bounds__(256)
__global__ void f32_to_bf16_kernel(const float* __restrict__ in, unsigned short* __restrict__ out, int n4) {
  int i = blockIdx.x * 256 + threadIdx.x;
  if (i >= n4) return;
  float4 v = ((const float4*)in)[i];
  uint2 p;
  p.x = (unsigned)f2b(v.x) | ((unsigned)f2b(v.y) << 16);
  p.y = (unsigned)f2b(v.z) | ((unsigned)f2b(v.w) << 16);
  ((uint2*)out)[i] = p;
}

// ---------------- dBC[:, :128] -> bf16 packed [L][128] ----------------------
__launch_bounds__(256)
__global__ void dbc_to_bf16_kernel(const float* __restrict__ dBC, unsigned short* __restrict__ dtb) {
  int i = blockIdx.x * 256 + threadIdx.x;  // over L*128
  int l = i >> 7, j = i & 127;
  dtb[i] = f2b(dBC[(size_t)l * DBC_ + j]);
}

// ---------------- bf16 MFMA GEMM: C[m][n] = sum_k A[m][k]*W[n][k] -----------
// 128x128 tile, 4 waves (2x2), 4x4 16x16x32 frags/wave.
// EPI 0: store; 1: softplus(acc+aux[n]); 2: acc + aux[m*N+n]
template<int EPI>
__launch_bounds__(256)
__global__ void gemm_bf16_mfma(const unsigned short* __restrict__ A,
                               const unsigned short* __restrict__ W,
                               float* __restrict__ C, int M, int N, int K,
                               const float* __restrict__ aux) {
  __shared__ unsigned short As[128 * 32];
  __shared__ unsigned short Ws[128 * 32];
  int bm = blockIdx.y * 128, bn = blockIdx.x * 128;
  int tid = threadIdx.x;
  int w = tid >> 6, lane = tid & 63;
  int wr = (w >> 1) * 64, wc = (w & 1) * 64;
  f32x4 acc[4][4];
#pragma unroll
  for (int m = 0; m < 4; m++)
#pragma unroll
    for (int n = 0; n < 4; n++) acc[m][n] = (f32x4){0.f, 0.f, 0.f, 0.f};

  int kb = lane >> 4, r = lane & 15;
  for (int k0 = 0; k0 < K; k0 += 32) {
#pragma unroll
    for (int i = 0; i < 2; i++) {
      int ch = (i * 4 + w) * 64 + lane;      // 0..511, lane-contiguous per wave
      int row = ch >> 2, kc = ch & 3;
      gload_lds16(A + (size_t)(bm + row) * K + k0 + kc * 8, As + ch * 8);
      gload_lds16(W + (size_t)(bn + row) * K + k0 + kc * 8, Ws + ch * 8);
    }
    asm volatile("s_waitcnt vmcnt(0)" ::: "memory");
    __syncthreads();
    s16x8 a[4], b[4];
#pragma unroll
    for (int m = 0; m < 4; m++)
      a[m] = *(const s16x8*)(As + (wr + m * 16 + r) * 32 + kb * 8);
#pragma unroll
    for (int n = 0; n < 4; n++)
      b[n] = *(const s16x8*)(Ws + (wc + n * 16 + r) * 32 + kb * 8);
#pragma unroll
    for (int m = 0; m < 4; m++)
#pragma unroll
      for (int n = 0; n < 4; n++)
        acc[m][n] = __builtin_amdgcn_mfma_f32_16x16x32_bf16(a[m], b[n], acc[m][n], 0, 0, 0);
    __syncthreads();
  }
  int q = lane >> 4;
#pragma unroll
  for (int m = 0; m < 4; m++) {
#pragma unroll
    for (int n = 0; n < 4; n++) {
#pragma unroll
      for (int j = 0; j < 4; j++) {
        int row = bm + wr + m * 16 + q * 4 + j;
        int col = bn + wc + n * 16 + r;
        float v = acc[m][n][j];
        if (EPI == 1) {
          v += aux[col];
          v = fmaxf(v, 0.f) + log1pf(__expf(-fabsf(v)));
        }
        if (EPI == 2) v += aux[(size_t)row * N + col];
        C[(size_t)row * N + col] = v;
      }
    }
  }
}

// ---------------- bf16 MFMA GEMM, BM=64 x BN=128 (for small-M grids) --------
// 4 waves (2x2), each 32x64: 2x4 frags. EPI 2: acc + aux[m*N+n]
template<int EPI>
__launch_bounds__(256)
__global__ void gemm_bf16_mfma_bm64(const unsigned short* __restrict__ A,
                                    const unsigned short* __restrict__ W,
                                    float* __restrict__ C, int M, int N, int K,
                                    const float* __restrict__ aux) {
  __shared__ unsigned short As[64 * 32];
  __shared__ unsigned short Ws[128 * 32];
  int bm = blockIdx.y * 64, bn = blockIdx.x * 128;
  int tid = threadIdx.x;
  int w = tid >> 6, lane = tid & 63;
  int wr = (w >> 1) * 32, wc = (w & 1) * 64;
  f32x4 acc[2][4];
#pragma unroll
  for (int m = 0; m < 2; m++)
#pragma unroll
    for (int n = 0; n < 4; n++) acc[m][n] = (f32x4){0.f, 0.f, 0.f, 0.f};

  int kb = lane >> 4, r = lane & 15;
  for (int k0 = 0; k0 < K; k0 += 32) {
    {
      int ch = w * 64 + lane;                // 0..255
      int row = ch >> 2, kc = ch & 3;
      gload_lds16(A + (size_t)(bm + row) * K + k0 + kc * 8, As + ch * 8);
    }
#pragma unroll
    for (int i = 0; i < 2; i++) {
      int ch = (i * 4 + w) * 64 + lane;      // 0..511
      int row = ch >> 2, kc = ch & 3;
      gload_lds16(W + (size_t)(bn + row) * K + k0 + kc * 8, Ws + ch * 8);
    }
    asm volatile("s_waitcnt vmcnt(0)" ::: "memory");
    __syncthreads();
    s16x8 a[2], b[4];
#pragma unroll
    for (int m = 0; m < 2; m++)
      a[m] = *(const s16x8*)(As + (wr + m * 16 + r) * 32 + kb * 8);
#pragma unroll
    for (int n = 0; n < 4; n++)
      b[n] = *(const s16x8*)(Ws + (wc + n * 16 + r) * 32 + kb * 8);
#pragma unroll
    for (int m = 0; m < 2; m++)
#pragma unroll
      for (int n = 0; n < 4; n++)
        acc[m][n] = __builtin_amdgcn_mfma_f32_16x16x32_bf16(a[m], b[n], acc[m][n], 0, 0, 0);
    __syncthreads();
  }
  int q = lane >> 4;
#pragma unroll
  for (int m = 0; m < 2; m++) {
#pragma unroll
    for (int n = 0; n < 4; n++) {
#pragma unroll
      for (int j = 0; j < 4; j++) {
        int row = bm + wr + m * 16 + q * 4 + j;
        int col = bn + wc + n * 16 + r;
        float v = acc[m][n][j];
        if (EPI == 2) v += aux[(size_t)row * N + col];
        C[(size_t)row * N + col] = v;
      }
    }
  }
}

// ---------------- depthwise conv1d (K=3, pad 1) + SiLU ----------------------
__launch_bounds__(256)
__global__ void conv_silu_kernel(const float* __restrict__ xz, const float* __restrict__ cw,
                                 const float* __restrict__ cb, float* __restrict__ xc) {
  int idx = blockIdx.x * 256 + threadIdx.x;  // over L*DI
  int l = idx >> 12, d = idx & (DI_ - 1);
  float w0 = cw[d * 3 + 0], w1 = cw[d * 3 + 1], w2 = cw[d * 3 + 2];
  float acc = cb[d];
  const float* base = xz + d;
  if (l > 0)      acc = fmaf(w0, base[(size_t)(l - 1) * (2 * DI_)], acc);
  acc = fmaf(w1, base[(size_t)l * (2 * DI_)], acc);
  if (l < L_ - 1) acc = fmaf(w2, base[(size_t)(l + 1) * (2 * DI_)], acc);
  float sig = 1.f / (1.f + __expf(-acc));
  xc[idx] = acc * sig;
}

// ---------------- An = -exp(A_log) ------------------------------------------
__global__ void negexp_kernel(const float* __restrict__ a, float* __restrict__ o, int n) {
  int i = blockIdx.x * 256 + threadIdx.x;
  if (i < n) o[i] = -__expf(a[i]);
}

// ---------------- xproj split-K stage1: part[s][l][n] partial dots ----------
__launch_bounds__(256)
__global__ void xproj_stage1(const float* __restrict__ xc, const float* __restrict__ W,
                             float* __restrict__ part) {
  __shared__ float xcs[64][68];
  __shared__ float Ws[160][68];
  int k0 = blockIdx.x * 256;
  int l0 = blockIdx.y * 64;
  int tid = threadIdx.x;
  int rg = tid >> 4;     // rows rg*4..+3
  int cg = tid & 15;     // cols cg*10..+9
  float acc[4][10] = {};
  for (int kc = 0; kc < 256; kc += 64) {
    for (int i = tid; i < 64 * 16; i += 256) {
      int row = i >> 4, c4 = (i & 15) * 4;
      *(float4*)&xcs[row][c4] = *(const float4*)&xc[(size_t)(l0 + row) * DI_ + k0 + kc + c4];
    }
    for (int i = tid; i < 160 * 16; i += 256) {
      int row = i >> 4, c4 = (i & 15) * 4;
      *(float4*)&Ws[row][c4] = *(const float4*)&W[(size_t)row * DI_ + k0 + kc + c4];
    }
    __syncthreads();
#pragma unroll 4
    for (int k = 0; k < 64; k += 4) {
      float4 xa[4];
#pragma unroll
      for (int i = 0; i < 4; i++) xa[i] = *(const float4*)&xcs[rg * 4 + i][k];
#pragma unroll
      for (int j = 0; j < 10; j++) {
        float4 wv = *(const float4*)&Ws[cg * 10 + j][k];
#pragma unroll
        for (int i = 0; i < 4; i++) {
          float s = acc[i][j];
          s = fmaf(xa[i].x, wv.x, s);
          s = fmaf(xa[i].y, wv.y, s);
          s = fmaf(xa[i].z, wv.z, s);
          s = fmaf(xa[i].w, wv.w, s);
          acc[i][j] = s;
        }
      }
    }
    __syncthreads();
  }
  float* pb = part + ((size_t)blockIdx.x * L_ + l0) * DBC_;
#pragma unroll
  for (int i = 0; i < 4; i++)
#pragma unroll
    for (int j = 0; j < 10; j++)
      pb[(size_t)(rg * 4 + i) * DBC_ + cg * 10 + j] = acc[i][j];
}

// ---------------- xproj stage2: dBC = sum over 16 splits --------------------
__launch_bounds__(256)
__global__ void xproj_stage2(const float* __restrict__ part, float* __restrict__ dBC) {
  int i = blockIdx.x * 256 + threadIdx.x;  // over L*DBC
  float s = 0.f;
#pragma unroll
  for (int sp = 0; sp < 16; sp++) s += part[(size_t)sp * (L_ * DBC_) + i];
  dBC[i] = s;
}

// ---------------- SSM elementwise, coalesced: 4 lanes per (l,d) -------------
// lane q in 0..3 owns s-quad q. h/h_out/An accesses are lane-contiguous 16B.
__launch_bounds__(256)
__global__ void ssm_kernel2(const float* __restrict__ xz, const float* __restrict__ xc,
                            const float* __restrict__ dBC, const float* __restrict__ delta,
                            const float* __restrict__ h, const float* __restrict__ An,
                            const float* __restrict__ Dp, float* __restrict__ h_out,
                            unsigned short* __restrict__ yzb) {
  int pair = threadIdx.x >> 2;           // 0..63 within block
  int q = threadIdx.x & 3;               // s-quad
  for (int base = blockIdx.x * 64; base < L_ * DI_; base += gridDim.x * 64) {
    int idx = base + pair;
    int l = idx >> 12, d = idx & (DI_ - 1);
    float dv = delta[idx];
    float xv = xc[idx];
    float4 hv = *(const float4*)(h + (size_t)idx * DS_ + q * 4);
    float4 Av = *(const float4*)(An + (size_t)d * DS_ + q * 4);
    float4 Bv = *(const float4*)(dBC + (size_t)l * DBC_ + DR_ + q * 4);
    float4 Cv = *(const float4*)(dBC + (size_t)l * DBC_ + DR_ + DS_ + q * 4);
    float4 hn;
    hn.x = __expf(dv * Av.x) * hv.x + dv * Bv.x * xv;
    hn.y = __expf(dv * Av.y) * hv.y + dv * Bv.y * xv;
    hn.z = __expf(dv * Av.z) * hv.z + dv * Bv.z * xv;
    hn.w = __expf(dv * Av.w) * hv.w + dv * Bv.w * xv;
    *(float4*)(h_out + (size_t)idx * DS_ + q * 4) = hn;
    float y = hn.x * Cv.x + hn.y * Cv.y + hn.z * Cv.z + hn.w * Cv.w;
    y += __shfl_xor(y, 1, 64);
    y += __shfl_xor(y, 2, 64);
    if (q == 0) {
      y = fmaf(Dp[d], xv, y);
      float zv = xz[(size_t)l * (2 * DI_) + DI_ + d];
      float sig = 1.f / (1.f + __expf(-zv));
      yzb[idx] = f2b(y * zv * sig);
    }
  }
}

extern "C" void kernel_launch(void* const* d_in, const int* in_sizes, int n_in,
                              void* d_out, int out_size, void* d_ws, size_t ws_size,
                              hipStream_t stream) {
  const float* x         = (const float*)d_in[0];
  const float* h         = (const float*)d_in[1];
  const float* norm_w    = (const float*)d_in[2];
  const float* in_proj_w = (const float*)d_in[3];
  const float* conv_w    = (const float*)d_in[4];
  const float* conv_b    = (const float*)d_in[5];
  const float* x_proj_w  = (const float*)d_in[6];
  const float* dt_proj_w = (const float*)d_in[7];
  const float* dt_proj_b = (const float*)d_in[8];
  const float* A_log     = (const float*)d_in[9];
  const float* Dvec      = (const float*)d_in[10];
  const float* out_projw = (const float*)d_in[11];

  float* out   = (float*)d_out;
  float* h_out = out + (size_t)L_ * DM_;

  float* ws    = (float*)d_ws;
  float* xn    = ws;                               // L*DM      = 2,097,152
  float* xz    = xn    + (size_t)L_ * DM_;         // L*2*DI    = 8,388,608
  float* xc    = xz    + (size_t)L_ * 2 * DI_;     // L*DI      = 4,194,304
  float* dBC   = xc    + (size_t)L_ * DI_;         // L*DBC     =   163,840
  float* delta = dBC   + (size_t)L_ * DBC_;        // L*DI      = 4,194,304
  float* An    = delta + (size_t)L_ * DI_;         // DI*DS     =    65,536
  float* part  = An    + (size_t)DI_ * DS_;        // 16*L*DBC  = 2,621,440
  unsigned short* xnb  = (unsigned short*)(part + (size_t)16 * L_ * DBC_);
  unsigned short* wib  = xnb  + (size_t)L_ * DM_;        // 2*DI*DM = 16,777,216
  unsigned short* wob  = wib  + (size_t)2 * DI_ * DM_;   // DM*DI   =  8,388,608
  unsigned short* yzb  = wob  + (size_t)DM_ * DI_;       // L*DI    =  4,194,304
  unsigned short* dtb  = yzb  + (size_t)L_ * DI_;        // L*DR    =   131,072
  unsigned short* dtwb = dtb  + (size_t)L_ * DR_;        // DI*DR   =   524,288

  // 1. RMSNorm (f32 + bf16 outputs)
  rmsnorm_kernel<<<L_, 256, 0, stream>>>(x, norm_w, xn, xnb);
  // 1b. weight conversions
  f32_to_bf16_kernel<<<(2 * DI_ * DM_ / 4 + 255) / 256, 256, 0, stream>>>(in_proj_w, wib, 2 * DI_ * DM_ / 4);
  f32_to_bf16_kernel<<<(DM_ * DI_ / 4 + 255) / 256, 256, 0, stream>>>(out_projw, wob, DM_ * DI_ / 4);
  f32_to_bf16_kernel<<<(DI_ * DR_ / 4 + 255) / 256, 256, 0, stream>>>(dt_proj_w, dtwb, DI_ * DR_ / 4);
  // 2. xz = xn @ in_proj_w.T   [1024 x 8192], K=2048  (bf16 MFMA)
  gemm_bf16_mfma<0><<<dim3(2 * DI_ / 128, L_ / 128), 256, 0, stream>>>(
      xnb, wib, xz, L_, 2 * DI_, DM_, nullptr);
  // 3. depthwise conv + silu -> xc
  conv_silu_kernel<<<L_ * DI_ / 256, 256, 0, stream>>>(xz, conv_w, conv_b, xc);
  // 4. An = -exp(A_log)
  negexp_kernel<<<(DI_ * DS_) / 256, 256, 0, stream>>>(A_log, An, DI_ * DS_);
  // 5. dBC = xc @ x_proj_w.T   [1024 x 160], K=4096  (split-K, 2 stages)
  xproj_stage1<<<dim3(16, 16), 256, 0, stream>>>(xc, x_proj_w, part);
  xproj_stage2<<<L_ * DBC_ / 256, 256, 0, stream>>>(part, dBC);
  // 5b. dBC[:, :128] -> bf16
  dbc_to_bf16_kernel<<<L_ * DR_ / 256, 256, 0, stream>>>(dBC, dtb);
  // 6. delta = softplus(dtb @ dt_proj_w.T + dt_proj_b)  [1024 x 4096], K=128 (bf16 MFMA)
  gemm_bf16_mfma<1><<<dim3(DI_ / 128, L_ / 128), 256, 0, stream>>>(
      dtb, dtwb, delta, L_, DI_, DR_, dt_proj_b);
  // 7. SSM elementwise: h_new (to output) + yz (bf16), coalesced
  ssm_kernel2<<<4096, 256, 0, stream>>>(
      xz, xc, dBC, delta, h, An, Dvec, h_out, yzb);
  // 8. out = yz @ out_proj_w.T + xn   [1024 x 2048], K=4096  (bf16 MFMA BM=64)
  gemm_bf16_mfma_bm64<2><<<dim3(DM_ / 128, L_ / 64), 256, 0, stream>>>(
      yzb, wob, out, L_, DM_, DI_, xn);
}

// Round 5
// 340.975 us; speedup vs baseline: 5.4348x; 1.1526x over previous
//
#include <hip/hip_runtime.h>
#include <hip/hip_bf16.h>
#include <math.h>

#define L_   1024
#define DM_  2048
#define DI_  4096
#define DR_  128
#define DS_  16
#define DBC_ 160   // DR + 2*DS

typedef __attribute__((ext_vector_type(4))) float f32x4;
typedef __attribute__((ext_vector_type(8))) short s16x8;

__device__ inline unsigned short f2b(float f) {  // RNE f32->bf16
  unsigned int u = __float_as_uint(f);
  u += 0x7fffu + ((u >> 16) & 1u);
  return (unsigned short)(u >> 16);
}
__device__ inline float b2f(unsigned short u) {
  return __uint_as_float(((unsigned int)u) << 16);
}

__device__ inline void gload_lds16(const void* g, void* l) {
  __builtin_amdgcn_global_load_lds(
      (const __attribute__((address_space(1))) void*)g,
      (__attribute__((address_space(3))) void*)l, 16, 0, 0);
}

// ---------------- RMSNorm: xn = x * rsqrt(mean(x^2)+eps) * w (f32 + bf16) ---
__launch_bounds__(256)
__global__ void rmsnorm_kernel(const float* __restrict__ x, const float* __restrict__ w,
                               float* __restrict__ xn, unsigned short* __restrict__ xnb) {
  int l = blockIdx.x;
  const float4* xr = (const float4*)(x + (size_t)l * DM_);
  const float4* wr = (const float4*)w;
  float4 v0 = xr[threadIdx.x];
  float4 v1 = xr[threadIdx.x + 256];
  float ss = v0.x*v0.x + v0.y*v0.y + v0.z*v0.z + v0.w*v0.w
           + v1.x*v1.x + v1.y*v1.y + v1.z*v1.z + v1.w*v1.w;
  for (int off = 32; off > 0; off >>= 1) ss += __shfl_down(ss, off, 64);
  __shared__ float sbuf[4];
  int lane = threadIdx.x & 63, wid = threadIdx.x >> 6;
  if (lane == 0) sbuf[wid] = ss;
  __syncthreads();
  float tot = sbuf[0] + sbuf[1] + sbuf[2] + sbuf[3];
  float scale = rsqrtf(tot / (float)DM_ + 1e-5f);
  float4 w0 = wr[threadIdx.x], w1 = wr[threadIdx.x + 256];
  float4 o0, o1;
  o0.x = v0.x * scale * w0.x; o0.y = v0.y * scale * w0.y;
  o0.z = v0.z * scale * w0.z; o0.w = v0.w * scale * w0.w;
  o1.x = v1.x * scale * w1.x; o1.y = v1.y * scale * w1.y;
  o1.z = v1.z * scale * w1.z; o1.w = v1.w * scale * w1.w;
  float4* outr = (float4*)(xn + (size_t)l * DM_);
  outr[threadIdx.x] = o0;
  outr[threadIdx.x + 256] = o1;
  uint2 p0, p1;
  p0.x = (unsigned)f2b(o0.x) | ((unsigned)f2b(o0.y) << 16);
  p0.y = (unsigned)f2b(o0.z) | ((unsigned)f2b(o0.w) << 16);
  p1.x = (unsigned)f2b(o1.x) | ((unsigned)f2b(o1.y) << 16);
  p1.y = (unsigned)f2b(o1.z) | ((unsigned)f2b(o1.w) << 16);
  uint2* ob = (uint2*)(xnb + (size_t)l * DM_);
  ob[threadIdx.x] = p0;
  ob[threadIdx.x + 256] = p1;
}

// ---------------- all weight conversions in one kernel ----------------------
__launch_bounds__(256)
__global__ void convert_weights_kernel(const float* __restrict__ w_in, const float* __restrict__ w_out,
                                       const float* __restrict__ w_dt, const float* __restrict__ w_xp,
                                       unsigned short* __restrict__ wib, unsigned short* __restrict__ wob,
                                       unsigned short* __restrict__ dtwb, unsigned short* __restrict__ xpwb) {
  const int N1 = 2 * DI_ * DM_ / 4;   // 4,194,304
  const int N2 = DM_ * DI_ / 4;       // 2,097,152
  const int N3 = DI_ * DR_ / 4;       //   131,072
  const int N4 = DBC_ * DI_ / 4;      //   163,840
  int i = blockIdx.x * 256 + threadIdx.x;
  const float* src; unsigned short* dst; int off;
  if (i < N1)                { src = w_in;  dst = wib;  off = i; }
  else if (i < N1 + N2)      { src = w_out; dst = wob;  off = i - N1; }
  else if (i < N1 + N2 + N3) { src = w_dt;  dst = dtwb; off = i - N1 - N2; }
  else if (i < N1 + N2 + N3 + N4) { src = w_xp; dst = xpwb; off = i - N1 - N2 - N3; }
  else return;
  float4 v = ((const float4*)src)[off];
  uint2 p;
  p.x = (unsigned)f2b(v.x) | ((unsigned)f2b(v.y) << 16);
  p.y = (unsigned)f2b(v.z) | ((unsigned)f2b(v.w) << 16);
  ((uint2*)dst)[off] = p;
}

// ---------------- bf16 MFMA GEMM: C[m][n] = sum_k A[m][k]*W[n][k] -----------
// 128x128 tile, 4 waves (2x2), 4x4 16x16x32 frags/wave.
// EPI 0: store; 1: softplus(acc+aux[n]); 2: acc + aux[m*N+n]
template<int EPI>
__launch_bounds__(256)
__global__ void gemm_bf16_mfma(const unsigned short* __restrict__ A,
                               const unsigned short* __restrict__ W,
                               float* __restrict__ C, int M, int N, int K,
                               const float* __restrict__ aux) {
  __shared__ unsigned short As[128 * 32];
  __shared__ unsigned short Ws[128 * 32];
  int bm = blockIdx.y * 128, bn = blockIdx.x * 128;
  int tid = threadIdx.x;
  int w = tid >> 6, lane = tid & 63;
  int wr = (w >> 1) * 64, wc = (w & 1) * 64;
  f32x4 acc[4][4];
#pragma unroll
  for (int m = 0; m < 4; m++)
#pragma unroll
    for (int n = 0; n < 4; n++) acc[m][n] = (f32x4){0.f, 0.f, 0.f, 0.f};

  int kb = lane >> 4, r = lane & 15;
  for (int k0 = 0; k0 < K; k0 += 32) {
#pragma unroll
    for (int i = 0; i < 2; i++) {
      int ch = (i * 4 + w) * 64 + lane;      // 0..511, lane-contiguous per wave
      int row = ch >> 2, kc = ch & 3;
      gload_lds16(A + (size_t)(bm + row) * K + k0 + kc * 8, As + ch * 8);
      gload_lds16(W + (size_t)(bn + row) * K + k0 + kc * 8, Ws + ch * 8);
    }
    asm volatile("s_waitcnt vmcnt(0)" ::: "memory");
    __syncthreads();
    s16x8 a[4], b[4];
#pragma unroll
    for (int m = 0; m < 4; m++)
      a[m] = *(const s16x8*)(As + (wr + m * 16 + r) * 32 + kb * 8);
#pragma unroll
    for (int n = 0; n < 4; n++)
      b[n] = *(const s16x8*)(Ws + (wc + n * 16 + r) * 32 + kb * 8);
#pragma unroll
    for (int m = 0; m < 4; m++)
#pragma unroll
      for (int n = 0; n < 4; n++)
        acc[m][n] = __builtin_amdgcn_mfma_f32_16x16x32_bf16(a[m], b[n], acc[m][n], 0, 0, 0);
    __syncthreads();
  }
  int q = lane >> 4;
#pragma unroll
  for (int m = 0; m < 4; m++) {
#pragma unroll
    for (int n = 0; n < 4; n++) {
#pragma unroll
      for (int j = 0; j < 4; j++) {
        int row = bm + wr + m * 16 + q * 4 + j;
        int col = bn + wc + n * 16 + r;
        float v = acc[m][n][j];
        if (EPI == 1) {
          v += aux[col];
          v = fmaxf(v, 0.f) + log1pf(__expf(-fabsf(v)));
        }
        if (EPI == 2) v += aux[(size_t)row * N + col];
        C[(size_t)row * N + col] = v;
      }
    }
  }
}

// ---------------- bf16 MFMA GEMM, BM=64 x BN=128 (for small-M grids) --------
template<int EPI>
__launch_bounds__(256)
__global__ void gemm_bf16_mfma_bm64(const unsigned short* __restrict__ A,
                                    const unsigned short* __restrict__ W,
                                    float* __restrict__ C, int M, int N, int K,
                                    const float* __restrict__ aux) {
  __shared__ unsigned short As[64 * 32];
  __shared__ unsigned short Ws[128 * 32];
  int bm = blockIdx.y * 64, bn = blockIdx.x * 128;
  int tid = threadIdx.x;
  int w = tid >> 6, lane = tid & 63;
  int wr = (w >> 1) * 32, wc = (w & 1) * 64;
  f32x4 acc[2][4];
#pragma unroll
  for (int m = 0; m < 2; m++)
#pragma unroll
    for (int n = 0; n < 4; n++) acc[m][n] = (f32x4){0.f, 0.f, 0.f, 0.f};

  int kb = lane >> 4, r = lane & 15;
  for (int k0 = 0; k0 < K; k0 += 32) {
    {
      int ch = w * 64 + lane;                // 0..255
      int row = ch >> 2, kc = ch & 3;
      gload_lds16(A + (size_t)(bm + row) * K + k0 + kc * 8, As + ch * 8);
    }
#pragma unroll
    for (int i = 0; i < 2; i++) {
      int ch = (i * 4 + w) * 64 + lane;      // 0..511
      int row = ch >> 2, kc = ch & 3;
      gload_lds16(W + (size_t)(bn + row) * K + k0 + kc * 8, Ws + ch * 8);
    }
    asm volatile("s_waitcnt vmcnt(0)" ::: "memory");
    __syncthreads();
    s16x8 a[2], b[4];
#pragma unroll
    for (int m = 0; m < 2; m++)
      a[m] = *(const s16x8*)(As + (wr + m * 16 + r) * 32 + kb * 8);
#pragma unroll
    for (int n = 0; n < 4; n++)
      b[n] = *(const s16x8*)(Ws + (wc + n * 16 + r) * 32 + kb * 8);
#pragma unroll
    for (int m = 0; m < 2; m++)
#pragma unroll
      for (int n = 0; n < 4; n++)
        acc[m][n] = __builtin_amdgcn_mfma_f32_16x16x32_bf16(a[m], b[n], acc[m][n], 0, 0, 0);
    __syncthreads();
  }
  int q = lane >> 4;
#pragma unroll
  for (int m = 0; m < 2; m++) {
#pragma unroll
    for (int n = 0; n < 4; n++) {
#pragma unroll
      for (int j = 0; j < 4; j++) {
        int row = bm + wr + m * 16 + q * 4 + j;
        int col = bn + wc + n * 16 + r;
        float v = acc[m][n][j];
        if (EPI == 2) v += aux[(size_t)row * N + col];
        C[(size_t)row * N + col] = v;
      }
    }
  }
}

// ---------------- depthwise conv1d (K=3, pad 1) + SiLU -> bf16 --------------
__launch_bounds__(256)
__global__ void conv_silu_kernel(const float* __restrict__ xz, const float* __restrict__ cw,
                                 const float* __restrict__ cb, unsigned short* __restrict__ xcb) {
  int idx = blockIdx.x * 256 + threadIdx.x;  // over L*DI
  int l = idx >> 12, d = idx & (DI_ - 1);
  float w0 = cw[d * 3 + 0], w1 = cw[d * 3 + 1], w2 = cw[d * 3 + 2];
  float acc = cb[d];
  const float* base = xz + d;
  if (l > 0)      acc = fmaf(w0, base[(size_t)(l - 1) * (2 * DI_)], acc);
  acc = fmaf(w1, base[(size_t)l * (2 * DI_)], acc);
  if (l < L_ - 1) acc = fmaf(w2, base[(size_t)(l + 1) * (2 * DI_)], acc);
  float sig = 1.f / (1.f + __expf(-acc));
  xcb[idx] = f2b(acc * sig);
}

// ---------------- xproj stage1, bf16 MFMA split-K ---------------------------
// grid (16 k-splits, 16 row-tiles of 64). Tile 64x160, 4 waves 2x2 (32x80).
__launch_bounds__(256)
__global__ void xproj_stage1_mfma(const unsigned short* __restrict__ xcb,
                                  const unsigned short* __restrict__ Wb,
                                  float* __restrict__ part) {
  __shared__ unsigned short As[64 * 32];
  __shared__ unsigned short Bs[160 * 32];
  int sp = blockIdx.x;
  int l0 = blockIdx.y * 64;
  int tid = threadIdx.x, w = tid >> 6, lane = tid & 63;
  int wr = (w >> 1) * 32, wc = (w & 1) * 80;
  int kb = lane >> 4, r = lane & 15;
  f32x4 acc[2][5];
#pragma unroll
  for (int m = 0; m < 2; m++)
#pragma unroll
    for (int n = 0; n < 5; n++) acc[m][n] = (f32x4){0.f, 0.f, 0.f, 0.f};

  for (int kt = 0; kt < 8; kt++) {
    int k0 = sp * 256 + kt * 32;
    {
      int ch = w * 64 + lane;                 // 0..255 -> A rows 0..63
      int row = ch >> 2, kc = ch & 3;
      gload_lds16(xcb + (size_t)(l0 + row) * DI_ + k0 + kc * 8, As + ch * 8);
    }
#pragma unroll
    for (int i = 0; i < 3; i++) {
      int g = i * 4 + w;                      // chunk-group; 10 groups of 64
      if (g < 10) {
        int ch = g * 64 + lane;               // 0..639 -> B rows 0..159
        int row = ch >> 2, kc = ch & 3;
        gload_lds16(Wb + (size_t)row * DI_ + k0 + kc * 8, Bs + ch * 8);
      }
    }
    asm volatile("s_waitcnt vmcnt(0)" ::: "memory");
    __syncthreads();
    s16x8 a[2], b[5];
#pragma unroll
    for (int m = 0; m < 2; m++)
      a[m] = *(const s16x8*)(As + (wr + m * 16 + r) * 32 + kb * 8);
#pragma unroll
    for (int n = 0; n < 5; n++)
      b[n] = *(const s16x8*)(Bs + (wc + n * 16 + r) * 32 + kb * 8);
#pragma unroll
    for (int m = 0; m < 2; m++)
#pragma unroll
      for (int n = 0; n < 5; n++)
        acc[m][n] = __builtin_amdgcn_mfma_f32_16x16x32_bf16(a[m], b[n], acc[m][n], 0, 0, 0);
    __syncthreads();
  }
  int q = lane >> 4;
  float* pb = part + (size_t)sp * (L_ * DBC_) + (size_t)l0 * DBC_;
#pragma unroll
  for (int m = 0; m < 2; m++)
#pragma unroll
    for (int n = 0; n < 5; n++)
#pragma unroll
      for (int j = 0; j < 4; j++)
        pb[(size_t)(wr + m * 16 + q * 4 + j) * DBC_ + wc + n * 16 + r] = acc[m][n][j];
}

// ---------------- xproj stage2: dBC = sum splits; also bf16 dt rows ---------
__launch_bounds__(256)
__global__ void xproj_stage2(const float* __restrict__ part, float* __restrict__ dBC,
                             unsigned short* __restrict__ dtb) {
  int i = blockIdx.x * 256 + threadIdx.x;  // over L*DBC
  float s = 0.f;
#pragma unroll
  for (int sp = 0; sp < 16; sp++) s += part[(size_t)sp * (L_ * DBC_) + i];
  dBC[i] = s;
  int l = i / DBC_, col = i - l * DBC_;
  if (col < DR_) dtb[(size_t)l * DR_ + col] = f2b(s);
}

// ---------------- SSM elementwise, coalesced: 4 lanes per (l,d) -------------
// lane q in 0..3 owns s-quad q. A_log -> -exp inline (negexp fused).
__launch_bounds__(256)
__global__ void ssm_kernel2(const float* __restrict__ xz, const unsigned short* __restrict__ xcb,
                            const float* __restrict__ dBC, const float* __restrict__ delta,
                            const float* __restrict__ h, const float* __restrict__ A_log,
                            const float* __restrict__ Dp, float* __restrict__ h_out,
                            unsigned short* __restrict__ yzb) {
  int pair = threadIdx.x >> 2;           // 0..63 within block
  int q = threadIdx.x & 3;               // s-quad
  for (int base = blockIdx.x * 64; base < L_ * DI_; base += gridDim.x * 64) {
    int idx = base + pair;
    int l = idx >> 12, d = idx & (DI_ - 1);
    float dv = delta[idx];
    float xv = b2f(xcb[idx]);
    float4 hv = *(const float4*)(h + (size_t)idx * DS_ + q * 4);
    float4 Al = *(const float4*)(A_log + (size_t)d * DS_ + q * 4);
    float4 Bv = *(const float4*)(dBC + (size_t)l * DBC_ + DR_ + q * 4);
    float4 Cv = *(const float4*)(dBC + (size_t)l * DBC_ + DR_ + DS_ + q * 4);
    float4 hn;
    hn.x = __expf(dv * -__expf(Al.x)) * hv.x + dv * Bv.x * xv;
    hn.y = __expf(dv * -__expf(Al.y)) * hv.y + dv * Bv.y * xv;
    hn.z = __expf(dv * -__expf(Al.z)) * hv.z + dv * Bv.z * xv;
    hn.w = __expf(dv * -__expf(Al.w)) * hv.w + dv * Bv.w * xv;
    *(float4*)(h_out + (size_t)idx * DS_ + q * 4) = hn;
    float y = hn.x * Cv.x + hn.y * Cv.y + hn.z * Cv.z + hn.w * Cv.w;
    y += __shfl_xor(y, 1, 64);
    y += __shfl_xor(y, 2, 64);
    if (q == 0) {
      y = fmaf(Dp[d], xv, y);
      float zv = xz[(size_t)l * (2 * DI_) + DI_ + d];
      float sig = 1.f / (1.f + __expf(-zv));
      yzb[idx] = f2b(y * zv * sig);
    }
  }
}

extern "C" void kernel_launch(void* const* d_in, const int* in_sizes, int n_in,
                              void* d_out, int out_size, void* d_ws, size_t ws_size,
                              hipStream_t stream) {
  const float* x         = (const float*)d_in[0];
  const float* h         = (const float*)d_in[1];
  const float* norm_w    = (const float*)d_in[2];
  const float* in_proj_w = (const float*)d_in[3];
  const float* conv_w    = (const float*)d_in[4];
  const float* conv_b    = (const float*)d_in[5];
  const float* x_proj_w  = (const float*)d_in[6];
  const float* dt_proj_w = (const float*)d_in[7];
  const float* dt_proj_b = (const float*)d_in[8];
  const float* A_log     = (const float*)d_in[9];
  const float* Dvec      = (const float*)d_in[10];
  const float* out_projw = (const float*)d_in[11];

  float* out   = (float*)d_out;
  float* h_out = out + (size_t)L_ * DM_;

  float* ws    = (float*)d_ws;
  float* xn    = ws;                               // L*DM      = 2,097,152
  float* xz    = xn    + (size_t)L_ * DM_;         // L*2*DI    = 8,388,608
  float* dBC   = xz    + (size_t)L_ * 2 * DI_;     // L*DBC     =   163,840
  float* delta = dBC   + (size_t)L_ * DBC_;        // L*DI      = 4,194,304
  float* part  = delta + (size_t)L_ * DI_;         // 16*L*DBC  = 2,621,440
  unsigned short* xnb  = (unsigned short*)(part + (size_t)16 * L_ * DBC_);
  unsigned short* wib  = xnb  + (size_t)L_ * DM_;        // 2*DI*DM = 16,777,216
  unsigned short* wob  = wib  + (size_t)2 * DI_ * DM_;   // DM*DI   =  8,388,608
  unsigned short* yzb  = wob  + (size_t)DM_ * DI_;       // L*DI    =  4,194,304
  unsigned short* dtb  = yzb  + (size_t)L_ * DI_;        // L*DR    =   131,072
  unsigned short* dtwb = dtb  + (size_t)L_ * DR_;        // DI*DR   =   524,288
  unsigned short* xpwb = dtwb + (size_t)DI_ * DR_;       // DBC*DI  =   655,360
  unsigned short* xcb  = xpwb + (size_t)DBC_ * DI_;      // L*DI    =  4,194,304

  // 1. RMSNorm (f32 + bf16 outputs)
  rmsnorm_kernel<<<L_, 256, 0, stream>>>(x, norm_w, xn, xnb);
  // 2. all weight conversions (in_proj, out_proj, dt_proj, x_proj)
  convert_weights_kernel<<<(2 * DI_ * DM_ + DM_ * DI_ + DI_ * DR_ + DBC_ * DI_) / 4 / 256, 256, 0, stream>>>(
      in_proj_w, out_projw, dt_proj_w, x_proj_w, wib, wob, dtwb, xpwb);
  // 3. xz = xn @ in_proj_w.T   [1024 x 8192], K=2048  (bf16 MFMA)
  gemm_bf16_mfma<0><<<dim3(2 * DI_ / 128, L_ / 128), 256, 0, stream>>>(
      xnb, wib, xz, L_, 2 * DI_, DM_, nullptr);
  // 4. depthwise conv + silu -> xcb (bf16)
  conv_silu_kernel<<<L_ * DI_ / 256, 256, 0, stream>>>(xz, conv_w, conv_b, xcb);
  // 5. dBC = xc @ x_proj_w.T   [1024 x 160], K=4096  (bf16 MFMA split-K)
  xproj_stage1_mfma<<<dim3(16, 16), 256, 0, stream>>>(xcb, xpwb, part);
  xproj_stage2<<<L_ * DBC_ / 256, 256, 0, stream>>>(part, dBC, dtb);
  // 6. delta = softplus(dtb @ dt_proj_w.T + dt_proj_b)  [1024 x 4096], K=128 (bf16 MFMA)
  gemm_bf16_mfma<1><<<dim3(DI_ / 128, L_ / 128), 256, 0, stream>>>(
      dtb, dtwb, delta, L_, DI_, DR_, dt_proj_b);
  // 7. SSM elementwise: h_new (to output) + yz (bf16); negexp fused
  ssm_kernel2<<<4096, 256, 0, stream>>>(
      xz, xcb, dBC, delta, h, A_log, Dvec, h_out, yzb);
  // 8. out = yz @ out_proj_w.T + xn   [1024 x 2048], K=4096  (bf16 MFMA BM=64)
  gemm_bf16_mfma_bm64<2><<<dim3(DM_ / 128, L_ / 64), 256, 0, stream>>>(
      yzb, wob, out, L_, DM_, DI_, xn);
}

// Round 6
// 330.725 us; speedup vs baseline: 5.6033x; 1.0310x over previous
//
#include <hip/hip_runtime.h>
#include <hip/hip_bf16.h>
#include <math.h>

#define L_   1024
#define DM_  2048
#define DI_  4096
#define DR_  128
#define DS_  16
#define DBC_ 160   // DR + 2*DS

typedef __attribute__((ext_vector_type(4))) float f32x4;
typedef __attribute__((ext_vector_type(8))) short s16x8;

__device__ inline unsigned short f2b(float f) {  // RNE f32->bf16
  unsigned int u = __float_as_uint(f);
  u += 0x7fffu + ((u >> 16) & 1u);
  return (unsigned short)(u >> 16);
}
__device__ inline float b2f(unsigned short u) {
  return __uint_as_float(((unsigned int)u) << 16);
}

__device__ inline void gload_lds16(const void* g, void* l) {
  __builtin_amdgcn_global_load_lds(
      (const __attribute__((address_space(1))) void*)g,
      (__attribute__((address_space(3))) void*)l, 16, 0, 0);
}

// ---- fused RMSNorm (blocks 0..1023) + weight f32->bf16 convert (rest) ------
__launch_bounds__(256)
__global__ void rms_convert_kernel(const float* __restrict__ x, const float* __restrict__ w,
                                   float* __restrict__ xn, unsigned short* __restrict__ xnb,
                                   const float* __restrict__ w_in, const float* __restrict__ w_out,
                                   const float* __restrict__ w_dt, const float* __restrict__ w_xp,
                                   unsigned short* __restrict__ wib, unsigned short* __restrict__ wob,
                                   unsigned short* __restrict__ dtwb, unsigned short* __restrict__ xpwb) {
  if (blockIdx.x < L_) {
    int l = blockIdx.x;
    const float4* xr = (const float4*)(x + (size_t)l * DM_);
    const float4* wr = (const float4*)w;
    float4 v0 = xr[threadIdx.x];
    float4 v1 = xr[threadIdx.x + 256];
    float ss = v0.x*v0.x + v0.y*v0.y + v0.z*v0.z + v0.w*v0.w
             + v1.x*v1.x + v1.y*v1.y + v1.z*v1.z + v1.w*v1.w;
    for (int off = 32; off > 0; off >>= 1) ss += __shfl_down(ss, off, 64);
    __shared__ float sbuf[4];
    int lane = threadIdx.x & 63, wid = threadIdx.x >> 6;
    if (lane == 0) sbuf[wid] = ss;
    __syncthreads();
    float tot = sbuf[0] + sbuf[1] + sbuf[2] + sbuf[3];
    float scale = rsqrtf(tot / (float)DM_ + 1e-5f);
    float4 w0 = wr[threadIdx.x], w1 = wr[threadIdx.x + 256];
    float4 o0, o1;
    o0.x = v0.x * scale * w0.x; o0.y = v0.y * scale * w0.y;
    o0.z = v0.z * scale * w0.z; o0.w = v0.w * scale * w0.w;
    o1.x = v1.x * scale * w1.x; o1.y = v1.y * scale * w1.y;
    o1.z = v1.z * scale * w1.z; o1.w = v1.w * scale * w1.w;
    float4* outr = (float4*)(xn + (size_t)l * DM_);
    outr[threadIdx.x] = o0;
    outr[threadIdx.x + 256] = o1;
    uint2 p0, p1;
    p0.x = (unsigned)f2b(o0.x) | ((unsigned)f2b(o0.y) << 16);
    p0.y = (unsigned)f2b(o0.z) | ((unsigned)f2b(o0.w) << 16);
    p1.x = (unsigned)f2b(o1.x) | ((unsigned)f2b(o1.y) << 16);
    p1.y = (unsigned)f2b(o1.z) | ((unsigned)f2b(o1.w) << 16);
    uint2* ob = (uint2*)(xnb + (size_t)l * DM_);
    ob[threadIdx.x] = p0;
    ob[threadIdx.x + 256] = p1;
    return;
  }
  const int N1 = 2 * DI_ * DM_ / 4;
  const int N2 = DM_ * DI_ / 4;
  const int N3 = DI_ * DR_ / 4;
  const int N4 = DBC_ * DI_ / 4;
  int i = (blockIdx.x - L_) * 256 + threadIdx.x;
  const float* src; unsigned short* dst; int off;
  if (i < N1)                { src = w_in;  dst = wib;  off = i; }
  else if (i < N1 + N2)      { src = w_out; dst = wob;  off = i - N1; }
  else if (i < N1 + N2 + N3) { src = w_dt;  dst = dtwb; off = i - N1 - N2; }
  else if (i < N1 + N2 + N3 + N4) { src = w_xp; dst = xpwb; off = i - N1 - N2 - N3; }
  else return;
  float4 v = ((const float4*)src)[off];
  uint2 p;
  p.x = (unsigned)f2b(v.x) | ((unsigned)f2b(v.y) << 16);
  p.y = (unsigned)f2b(v.z) | ((unsigned)f2b(v.w) << 16);
  ((uint2*)dst)[off] = p;
}

// ---------------- bf16 MFMA GEMM: C[m][n] = sum_k A[m][k]*W[n][k] -----------
// 128x128 tile, 4 waves (2x2), 4x4 16x16x32 frags/wave. XCD-swizzled grid.
// EPI 1: softplus(acc+aux[n]) -> bf16; EPI 3: plain -> bf16
template<int EPI>
__launch_bounds__(256)
__global__ void gemm_bf16_mfma(const unsigned short* __restrict__ A,
                               const unsigned short* __restrict__ W,
                               void* __restrict__ Cv_, int M, int N, int K,
                               const float* __restrict__ aux) {
  __shared__ unsigned short As[128 * 32];
  __shared__ unsigned short Ws[128 * 32];
  // bijective XCD swizzle (grid multiple of 8)
  int nwg = gridDim.x * gridDim.y;
  int flat = blockIdx.y * gridDim.x + blockIdx.x;
  int q8 = nwg >> 3;
  int swz = (flat & 7) * q8 + (flat >> 3);
  int bxi = swz % gridDim.x, byi = swz / gridDim.x;
  int bm = byi * 128, bn = bxi * 128;
  int tid = threadIdx.x;
  int w = tid >> 6, lane = tid & 63;
  int wr = (w >> 1) * 64, wc = (w & 1) * 64;
  f32x4 acc[4][4];
#pragma unroll
  for (int m = 0; m < 4; m++)
#pragma unroll
    for (int n = 0; n < 4; n++) acc[m][n] = (f32x4){0.f, 0.f, 0.f, 0.f};

  int kb = lane >> 4, r = lane & 15;
  for (int k0 = 0; k0 < K; k0 += 32) {
#pragma unroll
    for (int i = 0; i < 2; i++) {
      int ch = (i * 4 + w) * 64 + lane;      // 0..511, lane-contiguous per wave
      int row = ch >> 2, kc = ch & 3;
      gload_lds16(A + (size_t)(bm + row) * K + k0 + kc * 8, As + ch * 8);
      gload_lds16(W + (size_t)(bn + row) * K + k0 + kc * 8, Ws + ch * 8);
    }
    asm volatile("s_waitcnt vmcnt(0)" ::: "memory");
    __syncthreads();
    s16x8 a[4], b[4];
#pragma unroll
    for (int m = 0; m < 4; m++)
      a[m] = *(const s16x8*)(As + (wr + m * 16 + r) * 32 + kb * 8);
#pragma unroll
    for (int n = 0; n < 4; n++)
      b[n] = *(const s16x8*)(Ws + (wc + n * 16 + r) * 32 + kb * 8);
#pragma unroll
    for (int m = 0; m < 4; m++)
#pragma unroll
      for (int n = 0; n < 4; n++)
        acc[m][n] = __builtin_amdgcn_mfma_f32_16x16x32_bf16(a[m], b[n], acc[m][n], 0, 0, 0);
    __syncthreads();
  }
  int q = lane >> 4;
#pragma unroll
  for (int m = 0; m < 4; m++) {
#pragma unroll
    for (int n = 0; n < 4; n++) {
#pragma unroll
      for (int j = 0; j < 4; j++) {
        int row = bm + wr + m * 16 + q * 4 + j;
        int col = bn + wc + n * 16 + r;
        float v = acc[m][n][j];
        if (EPI == 1) {
          v += aux[col];
          v = fmaxf(v, 0.f) + log1pf(__expf(-fabsf(v)));
          ((unsigned short*)Cv_)[(size_t)row * N + col] = f2b(v);
        }
        if (EPI == 3) {
          ((unsigned short*)Cv_)[(size_t)row * N + col] = f2b(v);
        }
      }
    }
  }
}

// ---------------- bf16 MFMA GEMM, BM=64 x BN=128; EPI2: +aux, f32 out -------
__launch_bounds__(256)
__global__ void gemm_bf16_mfma_bm64(const unsigned short* __restrict__ A,
                                    const unsigned short* __restrict__ W,
                                    float* __restrict__ C, int M, int N, int K,
                                    const float* __restrict__ aux) {
  __shared__ unsigned short As[64 * 32];
  __shared__ unsigned short Ws[128 * 32];
  int nwg = gridDim.x * gridDim.y;
  int flat = blockIdx.y * gridDim.x + blockIdx.x;
  int q8 = nwg >> 3;
  int swz = (flat & 7) * q8 + (flat >> 3);
  int bxi = swz % gridDim.x, byi = swz / gridDim.x;
  int bm = byi * 64, bn = bxi * 128;
  int tid = threadIdx.x;
  int w = tid >> 6, lane = tid & 63;
  int wr = (w >> 1) * 32, wc = (w & 1) * 64;
  f32x4 acc[2][4];
#pragma unroll
  for (int m = 0; m < 2; m++)
#pragma unroll
    for (int n = 0; n < 4; n++) acc[m][n] = (f32x4){0.f, 0.f, 0.f, 0.f};

  int kb = lane >> 4, r = lane & 15;
  for (int k0 = 0; k0 < K; k0 += 32) {
    {
      int ch = w * 64 + lane;                // 0..255
      int row = ch >> 2, kc = ch & 3;
      gload_lds16(A + (size_t)(bm + row) * K + k0 + kc * 8, As + ch * 8);
    }
#pragma unroll
    for (int i = 0; i < 2; i++) {
      int ch = (i * 4 + w) * 64 + lane;      // 0..511
      int row = ch >> 2, kc = ch & 3;
      gload_lds16(W + (size_t)(bn + row) * K + k0 + kc * 8, Ws + ch * 8);
    }
    asm volatile("s_waitcnt vmcnt(0)" ::: "memory");
    __syncthreads();
    s16x8 a[2], b[4];
#pragma unroll
    for (int m = 0; m < 2; m++)
      a[m] = *(const s16x8*)(As + (wr + m * 16 + r) * 32 + kb * 8);
#pragma unroll
    for (int n = 0; n < 4; n++)
      b[n] = *(const s16x8*)(Ws + (wc + n * 16 + r) * 32 + kb * 8);
#pragma unroll
    for (int m = 0; m < 2; m++)
#pragma unroll
      for (int n = 0; n < 4; n++)
        acc[m][n] = __builtin_amdgcn_mfma_f32_16x16x32_bf16(a[m], b[n], acc[m][n], 0, 0, 0);
    __syncthreads();
  }
  int q = lane >> 4;
#pragma unroll
  for (int m = 0; m < 2; m++) {
#pragma unroll
    for (int n = 0; n < 4; n++) {
#pragma unroll
      for (int j = 0; j < 4; j++) {
        int row = bm + wr + m * 16 + q * 4 + j;
        int col = bn + wc + n * 16 + r;
        C[(size_t)row * N + col] = acc[m][n][j] + aux[(size_t)row * N + col];
      }
    }
  }
}

// ---------------- depthwise conv1d (K=3, pad 1) + SiLU: bf16 in/out ---------
__launch_bounds__(256)
__global__ void conv_silu_kernel(const unsigned short* __restrict__ xzb, const float* __restrict__ cw,
                                 const float* __restrict__ cb, unsigned short* __restrict__ xcb) {
  int idx = blockIdx.x * 256 + threadIdx.x;  // over L*DI
  int l = idx >> 12, d = idx & (DI_ - 1);
  float w0 = cw[d * 3 + 0], w1 = cw[d * 3 + 1], w2 = cw[d * 3 + 2];
  float acc = cb[d];
  const unsigned short* base = xzb + d;
  if (l > 0)      acc = fmaf(w0, b2f(base[(size_t)(l - 1) * (2 * DI_)]), acc);
  acc = fmaf(w1, b2f(base[(size_t)l * (2 * DI_)]), acc);
  if (l < L_ - 1) acc = fmaf(w2, b2f(base[(size_t)(l + 1) * (2 * DI_)]), acc);
  float sig = 1.f / (1.f + __expf(-acc));
  xcb[idx] = f2b(acc * sig);
}

// ---------------- xproj stage1, bf16 MFMA split-K ---------------------------
__launch_bounds__(256)
__global__ void xproj_stage1_mfma(const unsigned short* __restrict__ xcb,
                                  const unsigned short* __restrict__ Wb,
                                  float* __restrict__ part) {
  __shared__ unsigned short As[64 * 32];
  __shared__ unsigned short Bs[160 * 32];
  int sp = blockIdx.x;
  int l0 = blockIdx.y * 64;
  int tid = threadIdx.x, w = tid >> 6, lane = tid & 63;
  int wr = (w >> 1) * 32, wc = (w & 1) * 80;
  int kb = lane >> 4, r = lane & 15;
  f32x4 acc[2][5];
#pragma unroll
  for (int m = 0; m < 2; m++)
#pragma unroll
    for (int n = 0; n < 5; n++) acc[m][n] = (f32x4){0.f, 0.f, 0.f, 0.f};

  for (int kt = 0; kt < 8; kt++) {
    int k0 = sp * 256 + kt * 32;
    {
      int ch = w * 64 + lane;
      int row = ch >> 2, kc = ch & 3;
      gload_lds16(xcb + (size_t)(l0 + row) * DI_ + k0 + kc * 8, As + ch * 8);
    }
#pragma unroll
    for (int i = 0; i < 3; i++) {
      int g = i * 4 + w;
      if (g < 10) {
        int ch = g * 64 + lane;
        int row = ch >> 2, kc = ch & 3;
        gload_lds16(Wb + (size_t)row * DI_ + k0 + kc * 8, Bs + ch * 8);
      }
    }
    asm volatile("s_waitcnt vmcnt(0)" ::: "memory");
    __syncthreads();
    s16x8 a[2], b[5];
#pragma unroll
    for (int m = 0; m < 2; m++)
      a[m] = *(const s16x8*)(As + (wr + m * 16 + r) * 32 + kb * 8);
#pragma unroll
    for (int n = 0; n < 5; n++)
      b[n] = *(const s16x8*)(Bs + (wc + n * 16 + r) * 32 + kb * 8);
#pragma unroll
    for (int m = 0; m < 2; m++)
#pragma unroll
      for (int n = 0; n < 5; n++)
        acc[m][n] = __builtin_amdgcn_mfma_f32_16x16x32_bf16(a[m], b[n], acc[m][n], 0, 0, 0);
    __syncthreads();
  }
  int q = lane >> 4;
  float* pb = part + (size_t)sp * (L_ * DBC_) + (size_t)l0 * DBC_;
#pragma unroll
  for (int m = 0; m < 2; m++)
#pragma unroll
    for (int n = 0; n < 5; n++)
#pragma unroll
      for (int j = 0; j < 4; j++)
        pb[(size_t)(wr + m * 16 + q * 4 + j) * DBC_ + wc + n * 16 + r] = acc[m][n][j];
}

// ---------------- xproj stage2: dBC = sum splits; also bf16 dt rows ---------
__launch_bounds__(256)
__global__ void xproj_stage2(const float* __restrict__ part, float* __restrict__ dBC,
                             unsigned short* __restrict__ dtb) {
  int i = blockIdx.x * 256 + threadIdx.x;  // over L*DBC
  float s = 0.f;
#pragma unroll
  for (int sp = 0; sp < 16; sp++) s += part[(size_t)sp * (L_ * DBC_) + i];
  dBC[i] = s;
  int l = i / DBC_, col = i - l * DBC_;
  if (col < DR_) dtb[(size_t)l * DR_ + col] = f2b(s);
}

// ---------------- SSM elementwise, coalesced: 4 lanes per (l,d) -------------
__launch_bounds__(256)
__global__ void ssm_kernel2(const unsigned short* __restrict__ xzb, const unsigned short* __restrict__ xcb,
                            const float* __restrict__ dBC, const unsigned short* __restrict__ deltab,
                            const float* __restrict__ h, const float* __restrict__ A_log,
                            const float* __restrict__ Dp, float* __restrict__ h_out,
                            unsigned short* __restrict__ yzb) {
  int pair = threadIdx.x >> 2;           // 0..63 within block
  int q = threadIdx.x & 3;               // s-quad
  for (int base = blockIdx.x * 64; base < L_ * DI_; base += gridDim.x * 64) {
    int idx = base + pair;
    int l = idx >> 12, d = idx & (DI_ - 1);
    float dv = b2f(deltab[idx]);
    float xv = b2f(xcb[idx]);
    float4 hv = *(const float4*)(h + (size_t)idx * DS_ + q * 4);
    float4 Al = *(const float4*)(A_log + (size_t)d * DS_ + q * 4);
    float4 Bv = *(const float4*)(dBC + (size_t)l * DBC_ + DR_ + q * 4);
    float4 Cv = *(const float4*)(dBC + (size_t)l * DBC_ + DR_ + DS_ + q * 4);
    float4 hn;
    hn.x = __expf(dv * -__expf(Al.x)) * hv.x + dv * Bv.x * xv;
    hn.y = __expf(dv * -__expf(Al.y)) * hv.y + dv * Bv.y * xv;
    hn.z = __expf(dv * -__expf(Al.z)) * hv.z + dv * Bv.z * xv;
    hn.w = __expf(dv * -__expf(Al.w)) * hv.w + dv * Bv.w * xv;
    *(float4*)(h_out + (size_t)idx * DS_ + q * 4) = hn;
    float y = hn.x * Cv.x + hn.y * Cv.y + hn.z * Cv.z + hn.w * Cv.w;
    y += __shfl_xor(y, 1, 64);
    y += __shfl_xor(y, 2, 64);
    if (q == 0) {
      y = fmaf(Dp[d], xv, y);
      float zv = b2f(xzb[(size_t)l * (2 * DI_) + DI_ + d]);
      float sig = 1.f / (1.f + __expf(-zv));
      yzb[idx] = f2b(y * zv * sig);
    }
  }
}

extern "C" void kernel_launch(void* const* d_in, const int* in_sizes, int n_in,
                              void* d_out, int out_size, void* d_ws, size_t ws_size,
                              hipStream_t stream) {
  const float* x         = (const float*)d_in[0];
  const float* h         = (const float*)d_in[1];
  const float* norm_w    = (const float*)d_in[2];
  const float* in_proj_w = (const float*)d_in[3];
  const float* conv_w    = (const float*)d_in[4];
  const float* conv_b    = (const float*)d_in[5];
  const float* x_proj_w  = (const float*)d_in[6];
  const float* dt_proj_w = (const float*)d_in[7];
  const float* dt_proj_b = (const float*)d_in[8];
  const float* A_log     = (const float*)d_in[9];
  const float* Dvec      = (const float*)d_in[10];
  const float* out_projw = (const float*)d_in[11];

  float* out   = (float*)d_out;
  float* h_out = out + (size_t)L_ * DM_;

  float* ws    = (float*)d_ws;
  float* xn    = ws;                               // L*DM      = 2,097,152 f
  float* dBC   = xn    + (size_t)L_ * DM_;         // L*DBC     =   163,840 f
  float* part  = dBC   + (size_t)L_ * DBC_;        // 16*L*DBC  = 2,621,440 f
  unsigned short* xnb   = (unsigned short*)(part + (size_t)16 * L_ * DBC_);
  unsigned short* wib   = xnb   + (size_t)L_ * DM_;       // 2*DI*DM = 16,777,216
  unsigned short* wob   = wib   + (size_t)2 * DI_ * DM_;  // DM*DI   =  8,388,608
  unsigned short* yzb   = wob   + (size_t)DM_ * DI_;      // L*DI    =  4,194,304
  unsigned short* dtb   = yzb   + (size_t)L_ * DI_;       // L*DR    =   131,072
  unsigned short* dtwb  = dtb   + (size_t)L_ * DR_;       // DI*DR   =   524,288
  unsigned short* xpwb  = dtwb  + (size_t)DI_ * DR_;      // DBC*DI  =   655,360
  unsigned short* xcb   = xpwb  + (size_t)DBC_ * DI_;     // L*DI    =  4,194,304
  unsigned short* xzb   = xcb   + (size_t)L_ * DI_;       // L*2*DI  =  8,388,608
  unsigned short* deltab= xzb   + (size_t)L_ * 2 * DI_;   // L*DI    =  4,194,304
  // ~19.5 MB f32 + ~95 MB bf16

  // 1. fused RMSNorm + weight conversions
  const int CONV_BLKS = (2 * DI_ * DM_ + DM_ * DI_ + DI_ * DR_ + DBC_ * DI_) / 4 / 256;
  rms_convert_kernel<<<L_ + CONV_BLKS, 256, 0, stream>>>(
      x, norm_w, xn, xnb, in_proj_w, out_projw, dt_proj_w, x_proj_w, wib, wob, dtwb, xpwb);
  // 2. xz = xn @ in_proj_w.T  [1024 x 8192], K=2048 -> bf16
  gemm_bf16_mfma<3><<<dim3(2 * DI_ / 128, L_ / 128), 256, 0, stream>>>(
      xnb, wib, xzb, L_, 2 * DI_, DM_, nullptr);
  // 3. depthwise conv + silu -> xcb (bf16)
  conv_silu_kernel<<<L_ * DI_ / 256, 256, 0, stream>>>(xzb, conv_w, conv_b, xcb);
  // 4. dBC = xc @ x_proj_w.T  [1024 x 160], K=4096 (bf16 MFMA split-K)
  xproj_stage1_mfma<<<dim3(16, 16), 256, 0, stream>>>(xcb, xpwb, part);
  xproj_stage2<<<L_ * DBC_ / 256, 256, 0, stream>>>(part, dBC, dtb);
  // 5. delta = softplus(dtb @ dt_proj_w.T + dt_proj_b) -> bf16, K=128
  gemm_bf16_mfma<1><<<dim3(DI_ / 128, L_ / 128), 256, 0, stream>>>(
      dtb, dtwb, deltab, L_, DI_, DR_, dt_proj_b);
  // 6. SSM elementwise: h_new (to output) + yz (bf16)
  ssm_kernel2<<<4096, 256, 0, stream>>>(
      xzb, xcb, dBC, deltab, h, A_log, Dvec, h_out, yzb);
  // 7. out = yz @ out_proj_w.T + xn  [1024 x 2048], K=4096 (BM=64)
  gemm_bf16_mfma_bm64<<<dim3(DM_ / 128, L_ / 64), 256, 0, stream>>>(
      yzb, wob, out, L_, DM_, DI_, xn);
}

// Round 7
// 322.392 us; speedup vs baseline: 5.7481x; 1.0258x over previous
//
#include <hip/hip_runtime.h>
#include <hip/hip_bf16.h>
#include <math.h>

#define L_   1024
#define DM_  2048
#define DI_  4096
#define DR_  128
#define DS_  16
#define DBC_ 160   // DR + 2*DS

typedef __attribute__((ext_vector_type(4))) float f32x4;
typedef __attribute__((ext_vector_type(8))) short s16x8;

__device__ inline unsigned short f2b(float f) {  // RNE f32->bf16
  unsigned int u = __float_as_uint(f);
  u += 0x7fffu + ((u >> 16) & 1u);
  return (unsigned short)(u >> 16);
}
__device__ inline float b2f(unsigned short u) {
  return __uint_as_float(((unsigned int)u) << 16);
}

__device__ inline void gload_lds16(const void* g, void* l) {
  __builtin_amdgcn_global_load_lds(
      (const __attribute__((address_space(1))) void*)g,
      (__attribute__((address_space(3))) void*)l, 16, 0, 0);
}

// ---- fused RMSNorm (blocks 0..1023) + weight f32->bf16 convert (rest) ------
__launch_bounds__(256)
__global__ void rms_convert_kernel(const float* __restrict__ x, const float* __restrict__ w,
                                   float* __restrict__ xn, unsigned short* __restrict__ xnb,
                                   const float* __restrict__ w_in, const float* __restrict__ w_out,
                                   const float* __restrict__ w_dt, const float* __restrict__ w_xp,
                                   unsigned short* __restrict__ wib, unsigned short* __restrict__ wob,
                                   unsigned short* __restrict__ dtwb, unsigned short* __restrict__ xpwb) {
  if (blockIdx.x < L_) {
    int l = blockIdx.x;
    const float4* xr = (const float4*)(x + (size_t)l * DM_);
    const float4* wr = (const float4*)w;
    float4 v0 = xr[threadIdx.x];
    float4 v1 = xr[threadIdx.x + 256];
    float ss = v0.x*v0.x + v0.y*v0.y + v0.z*v0.z + v0.w*v0.w
             + v1.x*v1.x + v1.y*v1.y + v1.z*v1.z + v1.w*v1.w;
    for (int off = 32; off > 0; off >>= 1) ss += __shfl_down(ss, off, 64);
    __shared__ float sbuf[4];
    int lane = threadIdx.x & 63, wid = threadIdx.x >> 6;
    if (lane == 0) sbuf[wid] = ss;
    __syncthreads();
    float tot = sbuf[0] + sbuf[1] + sbuf[2] + sbuf[3];
    float scale = rsqrtf(tot / (float)DM_ + 1e-5f);
    float4 w0 = wr[threadIdx.x], w1 = wr[threadIdx.x + 256];
    float4 o0, o1;
    o0.x = v0.x * scale * w0.x; o0.y = v0.y * scale * w0.y;
    o0.z = v0.z * scale * w0.z; o0.w = v0.w * scale * w0.w;
    o1.x = v1.x * scale * w1.x; o1.y = v1.y * scale * w1.y;
    o1.z = v1.z * scale * w1.z; o1.w = v1.w * scale * w1.w;
    float4* outr = (float4*)(xn + (size_t)l * DM_);
    outr[threadIdx.x] = o0;
    outr[threadIdx.x + 256] = o1;
    uint2 p0, p1;
    p0.x = (unsigned)f2b(o0.x) | ((unsigned)f2b(o0.y) << 16);
    p0.y = (unsigned)f2b(o0.z) | ((unsigned)f2b(o0.w) << 16);
    p1.x = (unsigned)f2b(o1.x) | ((unsigned)f2b(o1.y) << 16);
    p1.y = (unsigned)f2b(o1.z) | ((unsigned)f2b(o1.w) << 16);
    uint2* ob = (uint2*)(xnb + (size_t)l * DM_);
    ob[threadIdx.x] = p0;
    ob[threadIdx.x + 256] = p1;
    return;
  }
  const int N1 = 2 * DI_ * DM_ / 4;
  const int N2 = DM_ * DI_ / 4;
  const int N3 = DI_ * DR_ / 4;
  const int N4 = DBC_ * DI_ / 4;
  int i = (blockIdx.x - L_) * 256 + threadIdx.x;
  const float* src; unsigned short* dst; int off;
  if (i < N1)                { src = w_in;  dst = wib;  off = i; }
  else if (i < N1 + N2)      { src = w_out; dst = wob;  off = i - N1; }
  else if (i < N1 + N2 + N3) { src = w_dt;  dst = dtwb; off = i - N1 - N2; }
  else if (i < N1 + N2 + N3 + N4) { src = w_xp; dst = xpwb; off = i - N1 - N2 - N3; }
  else return;
  float4 v = ((const float4*)src)[off];
  uint2 p;
  p.x = (unsigned)f2b(v.x) | ((unsigned)f2b(v.y) << 16);
  p.y = (unsigned)f2b(v.z) | ((unsigned)f2b(v.w) << 16);
  ((uint2*)dst)[off] = p;
}

// ---------------- bf16 MFMA GEMM: C[m][n] = sum_k A[m][k]*W[n][k] -----------
// 128x128 tile, 4 waves (2x2), 4x4 16x16x32 frags/wave. XCD-swizzled grid.
// 2-phase double-buffered LDS: STAGE(next) issued before compute(cur);
// __syncthreads' implicit vmcnt(0) drains next-tile loads after compute.
// EPI 1: softplus(acc+aux[n]) -> bf16; EPI 3: plain -> bf16
template<int EPI>
__launch_bounds__(256)
__global__ void gemm_bf16_mfma(const unsigned short* __restrict__ A,
                               const unsigned short* __restrict__ W,
                               void* __restrict__ Cv_, int M, int N, int K,
                               const float* __restrict__ aux) {
  __shared__ unsigned short As[2][128 * 32];
  __shared__ unsigned short Ws[2][128 * 32];
  int nwg = gridDim.x * gridDim.y;
  int flat = blockIdx.y * gridDim.x + blockIdx.x;
  int q8 = nwg >> 3;
  int swz = (flat & 7) * q8 + (flat >> 3);
  int bxi = swz % gridDim.x, byi = swz / gridDim.x;
  int bm = byi * 128, bn = bxi * 128;
  int tid = threadIdx.x;
  int w = tid >> 6, lane = tid & 63;
  int wr = (w >> 1) * 64, wc = (w & 1) * 64;
  // staging geometry (per tile): 512 chunks of 16B each for A and W
  int ch0 = w * 64 + lane, ch1 = (4 + w) * 64 + lane;
  int row0 = ch0 >> 2, kc0 = ch0 & 3;
  int row1 = ch1 >> 2, kc1 = ch1 & 3;

  f32x4 acc[4][4];
#pragma unroll
  for (int m = 0; m < 4; m++)
#pragma unroll
    for (int n = 0; n < 4; n++) acc[m][n] = (f32x4){0.f, 0.f, 0.f, 0.f};

  int kb = lane >> 4, r = lane & 15;

#define STAGE_(buf, k0)                                                          \
  do {                                                                           \
    gload_lds16(A + (size_t)(bm + row0) * K + (k0) + kc0 * 8, &As[buf][ch0 * 8]);\
    gload_lds16(W + (size_t)(bn + row0) * K + (k0) + kc0 * 8, &Ws[buf][ch0 * 8]);\
    gload_lds16(A + (size_t)(bm + row1) * K + (k0) + kc1 * 8, &As[buf][ch1 * 8]);\
    gload_lds16(W + (size_t)(bn + row1) * K + (k0) + kc1 * 8, &Ws[buf][ch1 * 8]);\
  } while (0)

  STAGE_(0, 0);
  __syncthreads();                       // drains vmcnt(0): buf0 ready
  int nt = K >> 5;
  for (int t = 0; t < nt; t++) {
    int cur = t & 1;
    if (t + 1 < nt) STAGE_(cur ^ 1, (t + 1) * 32);   // loads fly under compute
    s16x8 a[4], b[4];
#pragma unroll
    for (int m = 0; m < 4; m++)
      a[m] = *(const s16x8*)(&As[cur][(wr + m * 16 + r) * 32 + kb * 8]);
#pragma unroll
    for (int n = 0; n < 4; n++)
      b[n] = *(const s16x8*)(&Ws[cur][(wc + n * 16 + r) * 32 + kb * 8]);
#pragma unroll
    for (int m = 0; m < 4; m++)
#pragma unroll
      for (int n = 0; n < 4; n++)
        acc[m][n] = __builtin_amdgcn_mfma_f32_16x16x32_bf16(a[m], b[n], acc[m][n], 0, 0, 0);
    __syncthreads();                     // drains next-tile loads + read fence
  }
#undef STAGE_
  int q = lane >> 4;
#pragma unroll
  for (int m = 0; m < 4; m++) {
#pragma unroll
    for (int n = 0; n < 4; n++) {
#pragma unroll
      for (int j = 0; j < 4; j++) {
        int row = bm + wr + m * 16 + q * 4 + j;
        int col = bn + wc + n * 16 + r;
        float v = acc[m][n][j];
        if (EPI == 1) {
          v += aux[col];
          v = fmaxf(v, 0.f) + log1pf(__expf(-fabsf(v)));
          ((unsigned short*)Cv_)[(size_t)row * N + col] = f2b(v);
        }
        if (EPI == 3) {
          ((unsigned short*)Cv_)[(size_t)row * N + col] = f2b(v);
        }
      }
    }
  }
}

// ---------------- bf16 MFMA GEMM, BM=64 x BN=128; +aux, f32 out; 2-phase ----
__launch_bounds__(256)
__global__ void gemm_bf16_mfma_bm64(const unsigned short* __restrict__ A,
                                    const unsigned short* __restrict__ W,
                                    float* __restrict__ C, int M, int N, int K,
                                    const float* __restrict__ aux) {
  __shared__ unsigned short As[2][64 * 32];
  __shared__ unsigned short Ws[2][128 * 32];
  int nwg = gridDim.x * gridDim.y;
  int flat = blockIdx.y * gridDim.x + blockIdx.x;
  int q8 = nwg >> 3;
  int swz = (flat & 7) * q8 + (flat >> 3);
  int bxi = swz % gridDim.x, byi = swz / gridDim.x;
  int bm = byi * 64, bn = bxi * 128;
  int tid = threadIdx.x;
  int w = tid >> 6, lane = tid & 63;
  int wr = (w >> 1) * 32, wc = (w & 1) * 64;
  int chA = w * 64 + lane;               // 0..255
  int rowA = chA >> 2, kcA = chA & 3;
  int ch0 = w * 64 + lane, ch1 = (4 + w) * 64 + lane;
  int row0 = ch0 >> 2, kc0 = ch0 & 3;
  int row1 = ch1 >> 2, kc1 = ch1 & 3;
  f32x4 acc[2][4];
#pragma unroll
  for (int m = 0; m < 2; m++)
#pragma unroll
    for (int n = 0; n < 4; n++) acc[m][n] = (f32x4){0.f, 0.f, 0.f, 0.f};

  int kb = lane >> 4, r = lane & 15;

#define STAGE_(buf, k0)                                                          \
  do {                                                                           \
    gload_lds16(A + (size_t)(bm + rowA) * K + (k0) + kcA * 8, &As[buf][chA * 8]);\
    gload_lds16(W + (size_t)(bn + row0) * K + (k0) + kc0 * 8, &Ws[buf][ch0 * 8]);\
    gload_lds16(W + (size_t)(bn + row1) * K + (k0) + kc1 * 8, &Ws[buf][ch1 * 8]);\
  } while (0)

  STAGE_(0, 0);
  __syncthreads();
  int nt = K >> 5;
  for (int t = 0; t < nt; t++) {
    int cur = t & 1;
    if (t + 1 < nt) STAGE_(cur ^ 1, (t + 1) * 32);
    s16x8 a[2], b[4];
#pragma unroll
    for (int m = 0; m < 2; m++)
      a[m] = *(const s16x8*)(&As[cur][(wr + m * 16 + r) * 32 + kb * 8]);
#pragma unroll
    for (int n = 0; n < 4; n++)
      b[n] = *(const s16x8*)(&Ws[cur][(wc + n * 16 + r) * 32 + kb * 8]);
#pragma unroll
    for (int m = 0; m < 2; m++)
#pragma unroll
      for (int n = 0; n < 4; n++)
        acc[m][n] = __builtin_amdgcn_mfma_f32_16x16x32_bf16(a[m], b[n], acc[m][n], 0, 0, 0);
    __syncthreads();
  }
#undef STAGE_
  int q = lane >> 4;
#pragma unroll
  for (int m = 0; m < 2; m++) {
#pragma unroll
    for (int n = 0; n < 4; n++) {
#pragma unroll
      for (int j = 0; j < 4; j++) {
        int row = bm + wr + m * 16 + q * 4 + j;
        int col = bn + wc + n * 16 + r;
        C[(size_t)row * N + col] = acc[m][n][j] + aux[(size_t)row * N + col];
      }
    }
  }
}

// ---------------- depthwise conv1d (K=3, pad 1) + SiLU: bf16 in/out ---------
__launch_bounds__(256)
__global__ void conv_silu_kernel(const unsigned short* __restrict__ xzb, const float* __restrict__ cw,
                                 const float* __restrict__ cb, unsigned short* __restrict__ xcb) {
  int idx = blockIdx.x * 256 + threadIdx.x;  // over L*DI
  int l = idx >> 12, d = idx & (DI_ - 1);
  float w0 = cw[d * 3 + 0], w1 = cw[d * 3 + 1], w2 = cw[d * 3 + 2];
  float acc = cb[d];
  const unsigned short* base = xzb + d;
  if (l > 0)      acc = fmaf(w0, b2f(base[(size_t)(l - 1) * (2 * DI_)]), acc);
  acc = fmaf(w1, b2f(base[(size_t)l * (2 * DI_)]), acc);
  if (l < L_ - 1) acc = fmaf(w2, b2f(base[(size_t)(l + 1) * (2 * DI_)]), acc);
  float sig = 1.f / (1.f + __expf(-acc));
  xcb[idx] = f2b(acc * sig);
}

// ---------------- xproj stage1, bf16 MFMA split-K, 2-phase dbuf -------------
__launch_bounds__(256)
__global__ void xproj_stage1_mfma(const unsigned short* __restrict__ xcb,
                                  const unsigned short* __restrict__ Wb,
                                  float* __restrict__ part) {
  __shared__ unsigned short As[2][64 * 32];
  __shared__ unsigned short Bs[2][160 * 32];
  int sp = blockIdx.x;
  int l0 = blockIdx.y * 64;
  int tid = threadIdx.x, w = tid >> 6, lane = tid & 63;
  int wr = (w >> 1) * 32, wc = (w & 1) * 80;
  int kb = lane >> 4, r = lane & 15;
  int chA = w * 64 + lane;
  int rowA = chA >> 2, kcA = chA & 3;
  f32x4 acc[2][5];
#pragma unroll
  for (int m = 0; m < 2; m++)
#pragma unroll
    for (int n = 0; n < 5; n++) acc[m][n] = (f32x4){0.f, 0.f, 0.f, 0.f};

#define STAGE_(buf, k0)                                                            \
  do {                                                                             \
    gload_lds16(xcb + (size_t)(l0 + rowA) * DI_ + (k0) + kcA * 8, &As[buf][chA * 8]);\
    _Pragma("unroll")                                                              \
    for (int i = 0; i < 3; i++) {                                                  \
      int g = i * 4 + w;                                                           \
      if (g < 10) {                                                                \
        int ch = g * 64 + lane;                                                    \
        int row = ch >> 2, kc = ch & 3;                                            \
        gload_lds16(Wb + (size_t)row * DI_ + (k0) + kc * 8, &Bs[buf][ch * 8]);     \
      }                                                                            \
    }                                                                              \
  } while (0)

  int kbase = sp * 256;
  STAGE_(0, kbase);
  __syncthreads();
  for (int kt = 0; kt < 8; kt++) {
    int cur = kt & 1;
    if (kt + 1 < 8) STAGE_(cur ^ 1, kbase + (kt + 1) * 32);
    s16x8 a[2], b[5];
#pragma unroll
    for (int m = 0; m < 2; m++)
      a[m] = *(const s16x8*)(&As[cur][(wr + m * 16 + r) * 32 + kb * 8]);
#pragma unroll
    for (int n = 0; n < 5; n++)
      b[n] = *(const s16x8*)(&Bs[cur][(wc + n * 16 + r) * 32 + kb * 8]);
#pragma unroll
    for (int m = 0; m < 2; m++)
#pragma unroll
      for (int n = 0; n < 5; n++)
        acc[m][n] = __builtin_amdgcn_mfma_f32_16x16x32_bf16(a[m], b[n], acc[m][n], 0, 0, 0);
    __syncthreads();
  }
#undef STAGE_
  int q = lane >> 4;
  float* pb = part + (size_t)sp * (L_ * DBC_) + (size_t)l0 * DBC_;
#pragma unroll
  for (int m = 0; m < 2; m++)
#pragma unroll
    for (int n = 0; n < 5; n++)
#pragma unroll
      for (int j = 0; j < 4; j++)
        pb[(size_t)(wr + m * 16 + q * 4 + j) * DBC_ + wc + n * 16 + r] = acc[m][n][j];
}

// ---------------- xproj stage2: dBC = sum splits; also bf16 dt rows ---------
__launch_bounds__(256)
__global__ void xproj_stage2(const float* __restrict__ part, float* __restrict__ dBC,
                             unsigned short* __restrict__ dtb) {
  int i = blockIdx.x * 256 + threadIdx.x;  // over L*DBC
  float s = 0.f;
#pragma unroll
  for (int sp = 0; sp < 16; sp++) s += part[(size_t)sp * (L_ * DBC_) + i];
  dBC[i] = s;
  int l = i / DBC_, col = i - l * DBC_;
  if (col < DR_) dtb[(size_t)l * DR_ + col] = f2b(s);
}

// ---------------- SSM elementwise, coalesced: 4 lanes per (l,d) -------------
__launch_bounds__(256)
__global__ void ssm_kernel2(const unsigned short* __restrict__ xzb, const unsigned short* __restrict__ xcb,
                            const float* __restrict__ dBC, const unsigned short* __restrict__ deltab,
                            const float* __restrict__ h, const float* __restrict__ A_log,
                            const float* __restrict__ Dp, float* __restrict__ h_out,
                            unsigned short* __restrict__ yzb) {
  int pair = threadIdx.x >> 2;           // 0..63 within block
  int q = threadIdx.x & 3;               // s-quad
  for (int base = blockIdx.x * 64; base < L_ * DI_; base += gridDim.x * 64) {
    int idx = base + pair;
    int l = idx >> 12, d = idx & (DI_ - 1);
    float dv = b2f(deltab[idx]);
    float xv = b2f(xcb[idx]);
    float4 hv = *(const float4*)(h + (size_t)idx * DS_ + q * 4);
    float4 Al = *(const float4*)(A_log + (size_t)d * DS_ + q * 4);
    float4 Bv = *(const float4*)(dBC + (size_t)l * DBC_ + DR_ + q * 4);
    float4 Cv = *(const float4*)(dBC + (size_t)l * DBC_ + DR_ + DS_ + q * 4);
    float4 hn;
    hn.x = __expf(dv * -__expf(Al.x)) * hv.x + dv * Bv.x * xv;
    hn.y = __expf(dv * -__expf(Al.y)) * hv.y + dv * Bv.y * xv;
    hn.z = __expf(dv * -__expf(Al.z)) * hv.z + dv * Bv.z * xv;
    hn.w = __expf(dv * -__expf(Al.w)) * hv.w + dv * Bv.w * xv;
    *(float4*)(h_out + (size_t)idx * DS_ + q * 4) = hn;
    float y = hn.x * Cv.x + hn.y * Cv.y + hn.z * Cv.z + hn.w * Cv.w;
    y += __shfl_xor(y, 1, 64);
    y += __shfl_xor(y, 2, 64);
    if (q == 0) {
      y = fmaf(Dp[d], xv, y);
      float zv = b2f(xzb[(size_t)l * (2 * DI_) + DI_ + d]);
      float sig = 1.f / (1.f + __expf(-zv));
      yzb[idx] = f2b(y * zv * sig);
    }
  }
}

extern "C" void kernel_launch(void* const* d_in, const int* in_sizes, int n_in,
                              void* d_out, int out_size, void* d_ws, size_t ws_size,
                              hipStream_t stream) {
  const float* x         = (const float*)d_in[0];
  const float* h         = (const float*)d_in[1];
  const float* norm_w    = (const float*)d_in[2];
  const float* in_proj_w = (const float*)d_in[3];
  const float* conv_w    = (const float*)d_in[4];
  const float* conv_b    = (const float*)d_in[5];
  const float* x_proj_w  = (const float*)d_in[6];
  const float* dt_proj_w = (const float*)d_in[7];
  const float* dt_proj_b = (const float*)d_in[8];
  const float* A_log     = (const float*)d_in[9];
  const float* Dvec      = (const float*)d_in[10];
  const float* out_projw = (const float*)d_in[11];

  float* out   = (float*)d_out;
  float* h_out = out + (size_t)L_ * DM_;

  float* ws    = (float*)d_ws;
  float* xn    = ws;                               // L*DM      = 2,097,152 f
  float* dBC   = xn    + (size_t)L_ * DM_;         // L*DBC     =   163,840 f
  float* part  = dBC   + (size_t)L_ * DBC_;        // 16*L*DBC  = 2,621,440 f
  unsigned short* xnb   = (unsigned short*)(part + (size_t)16 * L_ * DBC_);
  unsigned short* wib   = xnb   + (size_t)L_ * DM_;       // 2*DI*DM = 16,777,216
  unsigned short* wob   = wib   + (size_t)2 * DI_ * DM_;  // DM*DI   =  8,388,608
  unsigned short* yzb   = wob   + (size_t)DM_ * DI_;      // L*DI    =  4,194,304
  unsigned short* dtb   = yzb   + (size_t)L_ * DI_;       // L*DR    =   131,072
  unsigned short* dtwb  = dtb   + (size_t)L_ * DR_;       // DI*DR   =   524,288
  unsigned short* xpwb  = dtwb  + (size_t)DI_ * DR_;      // DBC*DI  =   655,360
  unsigned short* xcb   = xpwb  + (size_t)DBC_ * DI_;     // L*DI    =  4,194,304
  unsigned short* xzb   = xcb   + (size_t)L_ * DI_;       // L*2*DI  =  8,388,608
  unsigned short* deltab= xzb   + (size_t)L_ * 2 * DI_;   // L*DI    =  4,194,304

  // 1. fused RMSNorm + weight conversions
  const int CONV_BLKS = (2 * DI_ * DM_ + DM_ * DI_ + DI_ * DR_ + DBC_ * DI_) / 4 / 256;
  rms_convert_kernel<<<L_ + CONV_BLKS, 256, 0, stream>>>(
      x, norm_w, xn, xnb, in_proj_w, out_projw, dt_proj_w, x_proj_w, wib, wob, dtwb, xpwb);
  // 2. xz = xn @ in_proj_w.T  [1024 x 8192], K=2048 -> bf16
  gemm_bf16_mfma<3><<<dim3(2 * DI_ / 128, L_ / 128), 256, 0, stream>>>(
      xnb, wib, xzb, L_, 2 * DI_, DM_, nullptr);
  // 3. depthwise conv + silu -> xcb (bf16)
  conv_silu_kernel<<<L_ * DI_ / 256, 256, 0, stream>>>(xzb, conv_w, conv_b, xcb);
  // 4. dBC = xc @ x_proj_w.T  [1024 x 160], K=4096 (bf16 MFMA split-K)
  xproj_stage1_mfma<<<dim3(16, 16), 256, 0, stream>>>(xcb, xpwb, part);
  xproj_stage2<<<L_ * DBC_ / 256, 256, 0, stream>>>(part, dBC, dtb);
  // 5. delta = softplus(dtb @ dt_proj_w.T + dt_proj_b) -> bf16, K=128
  gemm_bf16_mfma<1><<<dim3(DI_ / 128, L_ / 128), 256, 0, stream>>>(
      dtb, dtwb, deltab, L_, DI_, DR_, dt_proj_b);
  // 6. SSM elementwise: h_new (to output) + yz (bf16)
  ssm_kernel2<<<4096, 256, 0, stream>>>(
      xzb, xcb, dBC, deltab, h, A_log, Dvec, h_out, yzb);
  // 7. out = yz @ out_proj_w.T + xn  [1024 x 2048], K=4096 (BM=64)
  gemm_bf16_mfma_bm64<<<dim3(DM_ / 128, L_ / 64), 256, 0, stream>>>(
      yzb, wob, out, L_, DM_, DI_, xn);
}